// Round 3
// baseline (1671.933 us; speedup 1.0000x reference)
//
#include <hip/hip_runtime.h>

#define H 128
#define MB 64          // edges (or nodes) per block (legacy kernels)
#define LDA 264        // LDS row stride (elems) for block-tile kernels (+8 pad)
#define LDAW 268       // LDS row stride for wave-tile kernel (dword-stride 134 ≡ 6 mod 32 → 4-way)
#define LDB 136        // LDS row stride for [64 x 128] tiles (+8 pad)

typedef __attribute__((ext_vector_type(8))) short bf16x8;
typedef __attribute__((ext_vector_type(4))) short s16x4;
typedef __attribute__((ext_vector_type(4))) float f32x4;

__device__ __forceinline__ short f2bf(float f) {
    union { float f; unsigned u; } v; v.f = f;
    unsigned r = v.u + 0x7FFF + ((v.u >> 16) & 1);   // RTNE
    return (short)(r >> 16);
}
__device__ __forceinline__ float bf2f(short s) {
    union { unsigned u; float f; } v;
    v.u = ((unsigned)(unsigned short)s) << 16;
    return v.f;
}

// ---------------- weight prep: fp32 [K,N] -> bf16 transposed [N,K] ----------------
__global__ __launch_bounds__(256) void prep_weights(
    const float* __restrict__ W1, const float* __restrict__ W2,
    const float* __restrict__ WL,
    short* __restrict__ W1T, short* __restrict__ W2T, short* __restrict__ WLT)
{
    int tid = blockIdx.x * 256 + threadIdx.x;      // 0..32767
    {   // W1: [256,128] -> W1T [128][256]
        int n = tid >> 8, k = tid & 255;
        W1T[n * 256 + k] = f2bf(W1[k * 128 + n]);
    }
    if (tid < 16384) {  // W2, W_lift: [128,128] -> [128][128]
        int n = tid >> 7, k = tid & 127;
        W2T[n * 128 + k] = f2bf(W2[k * 128 + n]);
        WLT[n * 128 + k] = f2bf(WL[k * 128 + n]);
    }
}

// node_rep fp32 -> bf16 copy (halves the gather bytes in the edge kernel)
__global__ __launch_bounds__(256) void prep_nodes(
    const float* __restrict__ nr, short* __restrict__ nodeB, int total8)
{
    int t = blockIdx.x * 256 + threadIdx.x;
    if (t >= total8) return;
    const float4* p = (const float4*)nr + (size_t)t * 2;
    float4 a = p[0], b = p[1];
    bf16x8 v = { f2bf(a.x), f2bf(a.y), f2bf(a.z), f2bf(a.w),
                 f2bf(b.x), f2bf(b.y), f2bf(b.z), f2bf(b.w) };
    *(bf16x8*)(nodeB + (size_t)t * 8) = v;
}

// ---------------- CSR build ----------------
__global__ __launch_bounds__(256) void count_deg(
    const int* __restrict__ eidx, int* __restrict__ deg, int twoE)
{
    int t = blockIdx.x * 256 + threadIdx.x;
    if (t < twoE) atomicAdd(&deg[eidx[t]], 1);
}

// single-block exclusive scan of deg[N] -> row_start[N+1] and cursor[N]
__global__ __launch_bounds__(1024) void scan_deg(
    const int* __restrict__ deg, int* __restrict__ row_start,
    int* __restrict__ cursor, int N)
{
    __shared__ int part[1024];
    const int t = threadIdx.x;
    const int chunk = (N + 1023) >> 10;
    const int b = t * chunk;
    const int e = (b + chunk < N) ? (b + chunk) : N;
    int s = 0;
    for (int j = b; j < e; ++j) s += deg[j];
    part[t] = s;
    __syncthreads();
    for (int off = 1; off < 1024; off <<= 1) {
        int v = part[t];
        int u = (t >= off) ? part[t - off] : 0;
        __syncthreads();
        part[t] = v + u;
        __syncthreads();
    }
    int run = (t == 0) ? 0 : part[t - 1];
    for (int j = b; j < e; ++j) {
        int d = deg[j];
        row_start[j] = run;
        cursor[j]    = run;
        run += d;
    }
    if (t == 1023) row_start[N] = part[1023];
}

__global__ __launch_bounds__(256) void fill_csr(
    const int* __restrict__ eidx, int* __restrict__ cursor,
    int* __restrict__ csr, int E)
{
    int t = blockIdx.x * 256 + threadIdx.x;
    if (t < 2 * E) {
        int node = eidx[t];
        int e = (t < E) ? t : (t - E);
        int pos = atomicAdd(&cursor[node], 1);
        csr[pos] = e;
    }
}

// ---------------- PATH A: wave-independent edge kernel (NO __syncthreads) -----
// Each wave owns 16 edges in its private LDS slice. stage -> GEMM1 -> epilogue
// -> GEMM2 runs wave-synchronously; LDS ops within a wave are hardware-ordered,
// so no block barriers, no vmcnt(0) drains -- waves free-run and overlap.
__global__ __launch_bounds__(256) void edge_wave(
    const short* __restrict__ nodeB, const float* __restrict__ edge_rep,
    const int* __restrict__ eidx,
    const short* __restrict__ W1T, const short* __restrict__ WLT,
    const float* __restrict__ eps2p,
    short* __restrict__ hbuf, float* __restrict__ edge_out, int E)
{
    __shared__ short sA[4][16 * LDAW];   // per-wave slice: 16 rows x (128 lift | 128 edge)

    const int tid  = threadIdx.x;
    const int wid  = tid >> 6;
    const int lane = tid & 63;
    const int tile = blockIdx.x * 4 + wid;
    const int e0   = tile * 16;
    if (e0 >= E) return;                 // whole-wave exit
    const float e2 = 1.f + eps2p[0];
    short* sW = sA[wid];

    // ---- stage: 4 lanes per edge row, each covers 32 cols ----
    {
        int row  = lane >> 2;            // 0..15
        int cseg = (lane & 3) << 5;      // 0,32,64,96
        int e = e0 + row;
        short* rowA = sW + row * LDAW;
        if (e < E) {
            int sIdx = eidx[e], dIdx = eidx[E + e];
            const bf16x8* sp = (const bf16x8*)(nodeB + (size_t)sIdx * H + cseg);
            const bf16x8* dp = (const bf16x8*)(nodeB + (size_t)dIdx * H + cseg);
            const float4* ep = (const float4*)(edge_rep + (size_t)e * H + cseg);
            bf16x8 s_[4], d_[4];
            float4 ev[8];
            #pragma unroll
            for (int j = 0; j < 4; ++j) { s_[j] = sp[j]; d_[j] = dp[j]; }
            #pragma unroll
            for (int j = 0; j < 8; ++j) ev[j] = ep[j];
            #pragma unroll
            for (int j = 0; j < 4; ++j) {
                bf16x8 lift;
                #pragma unroll
                for (int k = 0; k < 8; ++k)
                    lift[k] = f2bf(bf2f(s_[j][k]) + bf2f(d_[j][k]));
                *(bf16x8*)&rowA[cseg + 8 * j] = lift;
            }
            #pragma unroll
            for (int j = 0; j < 8; ++j) {
                float4 c = ev[j];
                s16x4 er = { f2bf(c.x), f2bf(c.y), f2bf(c.z), f2bf(c.w) };
                *(s16x4*)&rowA[H + cseg + 4 * j] = er;
            }
        } else {
            s16x4 z = {0, 0, 0, 0};
            #pragma unroll
            for (int j = 0; j < 8; ++j) {
                int cc = cseg + 4 * j;
                *(s16x4*)&rowA[cc]     = z;
                *(s16x4*)&rowA[H + cc] = z;
            }
        }
    }
    asm volatile("" ::: "memory");       // compiler fence; wave LDS ops are HW-ordered

    const int m = lane & 15;             // A row / D col
    const int q = lane >> 4;             // k-quad / D row group

    // ---- GEMM1: [16,256] x [256,128] -> h ----
    f32x4 zero = {0.f, 0.f, 0.f, 0.f};
    f32x4 acc[8];
    #pragma unroll
    for (int nt = 0; nt < 8; ++nt) acc[nt] = zero;

    #pragma unroll
    for (int ks = 0; ks < 8; ++ks) {
        int k0 = ks * 32 + q * 8;
        bf16x8 aF = *(const bf16x8*)&sW[m * LDAW + k0];
        #pragma unroll
        for (int nt = 0; nt < 8; ++nt) {
            bf16x8 bF = *(const bf16x8*)&W1T[(nt * 16 + m) * 256 + k0];
            acc[nt] = __builtin_amdgcn_mfma_f32_16x16x32_bf16(aF, bF, acc[nt], 0, 0, 0);
        }
    }

    // ---- epilogue: relu, store h bf16, b2 = e2*h + lift (RMW own LDS slice) ----
    #pragma unroll
    for (int nt = 0; nt < 8; ++nt) {
        int col = nt * 16 + m;
        #pragma unroll
        for (int i = 0; i < 4; ++i) {
            int rr = (q << 2) + i;       // 0..15
            if (e0 + rr < E) {
                float h = acc[nt][i];
                h = h > 0.f ? h : 0.f;
                hbuf[(size_t)(e0 + rr) * H + col] = f2bf(h);
                float b2 = e2 * h + bf2f(sW[rr * LDAW + col]);
                sW[rr * LDAW + col] = f2bf(b2);
            }
        }
    }
    asm volatile("" ::: "memory");

    // ---- GEMM2: edge_out = relu(b2 @ W_lift) ----
    f32x4 acc2[8];
    #pragma unroll
    for (int nt = 0; nt < 8; ++nt) acc2[nt] = zero;

    #pragma unroll
    for (int ks = 0; ks < 4; ++ks) {
        int k0 = ks * 32 + q * 8;
        bf16x8 aF = *(const bf16x8*)&sW[m * LDAW + k0];
        #pragma unroll
        for (int nt = 0; nt < 8; ++nt) {
            bf16x8 bF = *(const bf16x8*)&WLT[(nt * 16 + m) * 128 + k0];
            acc2[nt] = __builtin_amdgcn_mfma_f32_16x16x32_bf16(aF, bF, acc2[nt], 0, 0, 0);
        }
    }

    #pragma unroll
    for (int nt = 0; nt < 8; ++nt) {
        int col = nt * 16 + m;
        #pragma unroll
        for (int i = 0; i < 4; ++i) {
            int rr = (q << 2) + i;
            if (e0 + rr < E) {
                float v = acc2[nt][i];
                edge_out[(size_t)(e0 + rr) * H + col] = v > 0.f ? v : 0.f;
            }
        }
    }
}

// ---------------- fallback fused edge kernel (block-tile, no nodeB) ----------
__global__ __launch_bounds__(256) void edge_fused_nb(
    const float* __restrict__ node_rep, const float* __restrict__ edge_rep,
    const int* __restrict__ eidx,
    const short* __restrict__ W1T, const short* __restrict__ WLT,
    const float* __restrict__ eps2p,
    short* __restrict__ hbuf, float* __restrict__ edge_out, int E)
{
    __shared__ short sA[MB * LDA];

    const int tid = threadIdx.x;
    const int e0  = blockIdx.x * MB;
    const float e2 = 1.f + eps2p[0];

    {
        int row  = tid >> 2;
        int cseg = (tid & 3) << 5;
        int e = e0 + row;
        short* rowA = sA + row * LDA;
        if (e < E) {
            int sIdx = eidx[e], dIdx = eidx[E + e];
            const float4* sp = (const float4*)(node_rep + (size_t)sIdx * H + cseg);
            const float4* dp = (const float4*)(node_rep + (size_t)dIdx * H + cseg);
            const float4* ep = (const float4*)(edge_rep + (size_t)e * H + cseg);
            #pragma unroll
            for (int j = 0; j < 8; ++j) {
                float4 a = sp[j], b = dp[j], c = ep[j];
                int cc = cseg + 4 * j;
                s16x4 lift = { f2bf(a.x + b.x), f2bf(a.y + b.y),
                               f2bf(a.z + b.z), f2bf(a.w + b.w) };
                s16x4 er   = { f2bf(c.x), f2bf(c.y), f2bf(c.z), f2bf(c.w) };
                *(s16x4*)&rowA[cc]      = lift;
                *(s16x4*)&rowA[H + cc]  = er;
            }
        } else {
            s16x4 z = {0, 0, 0, 0};
            #pragma unroll
            for (int j = 0; j < 8; ++j) {
                int cc = cseg + 4 * j;
                *(s16x4*)&rowA[cc]     = z;
                *(s16x4*)&rowA[H + cc] = z;
            }
        }
    }
    __syncthreads();

    const int wave = tid >> 6;
    const int lane = tid & 63;
    const int m = lane & 15;
    const int q = lane >> 4;

    f32x4 zero = {0.f, 0.f, 0.f, 0.f};
    f32x4 acc[4][2];
    #pragma unroll
    for (int mt = 0; mt < 4; ++mt)
        #pragma unroll
        for (int nt = 0; nt < 2; ++nt) acc[mt][nt] = zero;

    #pragma unroll
    for (int ks = 0; ks < 8; ++ks) {
        int k0 = ks * 32 + q * 8;
        bf16x8 aF[4];
        #pragma unroll
        for (int mt = 0; mt < 4; ++mt)
            aF[mt] = *(const bf16x8*)&sA[(mt * 16 + m) * LDA + k0];
        bf16x8 bF[2];
        #pragma unroll
        for (int nt = 0; nt < 2; ++nt) {
            int n = (wave << 5) + (nt << 4) + m;
            bF[nt] = *(const bf16x8*)&W1T[n * 256 + k0];
        }
        #pragma unroll
        for (int mt = 0; mt < 4; ++mt)
            #pragma unroll
            for (int nt = 0; nt < 2; ++nt)
                acc[mt][nt] = __builtin_amdgcn_mfma_f32_16x16x32_bf16(
                    aF[mt], bF[nt], acc[mt][nt], 0, 0, 0);
    }
    __syncthreads();

    #pragma unroll
    for (int mt = 0; mt < 4; ++mt) {
        #pragma unroll
        for (int nt = 0; nt < 2; ++nt) {
            int col = (wave << 5) + (nt << 4) + m;
            #pragma unroll
            for (int i = 0; i < 4; ++i) {
                int rr = (mt << 4) + (q << 2) + i;
                if (e0 + rr < E) {
                    float h = acc[mt][nt][i];
                    h = h > 0.f ? h : 0.f;
                    hbuf[(size_t)(e0 + rr) * H + col] = f2bf(h);
                    float b2 = e2 * h + bf2f(sA[rr * LDA + col]);
                    sA[rr * LDA + col] = f2bf(b2);
                }
            }
        }
    }
    __syncthreads();

    f32x4 acc2[4][2];
    #pragma unroll
    for (int mt = 0; mt < 4; ++mt)
        #pragma unroll
        for (int nt = 0; nt < 2; ++nt) acc2[mt][nt] = zero;

    #pragma unroll
    for (int ks = 0; ks < 4; ++ks) {
        int k0 = ks * 32 + q * 8;
        bf16x8 aF[4];
        #pragma unroll
        for (int mt = 0; mt < 4; ++mt)
            aF[mt] = *(const bf16x8*)&sA[(mt * 16 + m) * LDA + k0];
        bf16x8 bF[2];
        #pragma unroll
        for (int nt = 0; nt < 2; ++nt) {
            int n = (wave << 5) + (nt << 4) + m;
            bF[nt] = *(const bf16x8*)&WLT[n * 128 + k0];
        }
        #pragma unroll
        for (int mt = 0; mt < 4; ++mt)
            #pragma unroll
            for (int nt = 0; nt < 2; ++nt)
                acc2[mt][nt] = __builtin_amdgcn_mfma_f32_16x16x32_bf16(
                    aF[mt], bF[nt], acc2[mt][nt], 0, 0, 0);
    }

    #pragma unroll
    for (int mt = 0; mt < 4; ++mt) {
        #pragma unroll
        for (int nt = 0; nt < 2; ++nt) {
            int col = (wave << 5) + (nt << 4) + m;
            #pragma unroll
            for (int i = 0; i < 4; ++i) {
                int rr = (mt << 4) + (q << 2) + i;
                if (e0 + rr < E) {
                    float v = acc2[mt][nt][i];
                    edge_out[(size_t)(e0 + rr) * H + col] = v > 0.f ? v : 0.f;
                }
            }
        }
    }
}

// ---------------- PATH B: split edge kernels, h transits f32 via edge_out ----
__global__ __launch_bounds__(256) void edge_h_kernel(
    const float* __restrict__ node_rep, const float* __restrict__ edge_rep,
    const int* __restrict__ eidx, const short* __restrict__ W1T,
    float* __restrict__ hbuf, int E)
{
    __shared__ short sA[MB * LDA];
    const int tid = threadIdx.x;
    const int e0  = blockIdx.x * MB;
    {
        int row  = tid >> 2;
        int cseg = (tid & 3) << 5;
        int e = e0 + row;
        short* rowA = sA + row * LDA;
        if (e < E) {
            int sIdx = eidx[e], dIdx = eidx[E + e];
            const float4* sp = (const float4*)(node_rep + (size_t)sIdx * H + cseg);
            const float4* dp = (const float4*)(node_rep + (size_t)dIdx * H + cseg);
            const float4* ep = (const float4*)(edge_rep + (size_t)e * H + cseg);
            #pragma unroll
            for (int j = 0; j < 8; ++j) {
                float4 a = sp[j], b = dp[j], c = ep[j];
                int cc = cseg + 4 * j;
                s16x4 lift = { f2bf(a.x + b.x), f2bf(a.y + b.y),
                               f2bf(a.z + b.z), f2bf(a.w + b.w) };
                s16x4 er   = { f2bf(c.x), f2bf(c.y), f2bf(c.z), f2bf(c.w) };
                *(s16x4*)&rowA[cc]      = lift;
                *(s16x4*)&rowA[H + cc]  = er;
            }
        } else {
            s16x4 z = {0, 0, 0, 0};
            #pragma unroll
            for (int j = 0; j < 8; ++j) {
                int cc = cseg + 4 * j;
                *(s16x4*)&rowA[cc]     = z;
                *(s16x4*)&rowA[H + cc] = z;
            }
        }
    }
    __syncthreads();

    const int wave = tid >> 6;
    const int lane = tid & 63;
    const int m = lane & 15;
    const int q = lane >> 4;

    f32x4 zero = {0.f, 0.f, 0.f, 0.f};
    f32x4 acc[4][2];
    #pragma unroll
    for (int mt = 0; mt < 4; ++mt)
        #pragma unroll
        for (int nt = 0; nt < 2; ++nt) acc[mt][nt] = zero;

    #pragma unroll
    for (int ks = 0; ks < 8; ++ks) {
        int k0 = ks * 32 + q * 8;
        bf16x8 aF[4];
        #pragma unroll
        for (int mt = 0; mt < 4; ++mt)
            aF[mt] = *(const bf16x8*)&sA[(mt * 16 + m) * LDA + k0];
        bf16x8 bF[2];
        #pragma unroll
        for (int nt = 0; nt < 2; ++nt) {
            int n = (wave << 5) + (nt << 4) + m;
            bF[nt] = *(const bf16x8*)&W1T[n * 256 + k0];
        }
        #pragma unroll
        for (int mt = 0; mt < 4; ++mt)
            #pragma unroll
            for (int nt = 0; nt < 2; ++nt)
                acc[mt][nt] = __builtin_amdgcn_mfma_f32_16x16x32_bf16(
                    aF[mt], bF[nt], acc[mt][nt], 0, 0, 0);
    }

    #pragma unroll
    for (int mt = 0; mt < 4; ++mt) {
        #pragma unroll
        for (int nt = 0; nt < 2; ++nt) {
            int col = (wave << 5) + (nt << 4) + m;
            #pragma unroll
            for (int i = 0; i < 4; ++i) {
                int rr = (mt << 4) + (q << 2) + i;
                if (e0 + rr < E) {
                    float h = acc[mt][nt][i];
                    hbuf[(size_t)(e0 + rr) * H + col] = h > 0.f ? h : 0.f;
                }
            }
        }
    }
}

// finalize: edge_out = relu((e2*h + lift) @ W_lift); h f32 read from eo, written in place
__global__ __launch_bounds__(256) void edge_finalize(
    const float* __restrict__ node_rep, const int* __restrict__ eidx,
    const short* __restrict__ WLT, const float* __restrict__ eps2p,
    float* __restrict__ eo, int E)
{
    __shared__ short sB[MB * LDB];
    const int tid = threadIdx.x;
    const int e0  = blockIdx.x * MB;
    const float e2 = 1.f + eps2p[0];
    {
        int row  = tid >> 2;
        int cseg = (tid & 3) << 5;
        int e = e0 + row;
        short* rowB = sB + row * LDB;
        if (e < E) {
            int sIdx = eidx[e], dIdx = eidx[E + e];
            const float4* hp = (const float4*)(eo + (size_t)e * H + cseg);
            const float4* sp = (const float4*)(node_rep + (size_t)sIdx * H + cseg);
            const float4* dp = (const float4*)(node_rep + (size_t)dIdx * H + cseg);
            #pragma unroll
            for (int j = 0; j < 8; ++j) {
                float4 hv = hp[j], a = sp[j], b = dp[j];
                int cc = cseg + 4 * j;
                s16x4 v = { f2bf(e2 * hv.x + a.x + b.x), f2bf(e2 * hv.y + a.y + b.y),
                            f2bf(e2 * hv.z + a.z + b.z), f2bf(e2 * hv.w + a.w + b.w) };
                *(s16x4*)&rowB[cc] = v;
            }
        } else {
            s16x4 z = {0, 0, 0, 0};
            #pragma unroll
            for (int j = 0; j < 8; ++j) *(s16x4*)&rowB[cseg + 4 * j] = z;
        }
    }
    __syncthreads();

    const int wave = tid >> 6;
    const int lane = tid & 63;
    const int m = lane & 15;
    const int q = lane >> 4;

    f32x4 zero = {0.f, 0.f, 0.f, 0.f};
    f32x4 acc2[4][2];
    #pragma unroll
    for (int mt = 0; mt < 4; ++mt)
        #pragma unroll
        for (int nt = 0; nt < 2; ++nt) acc2[mt][nt] = zero;

    #pragma unroll
    for (int ks = 0; ks < 4; ++ks) {
        int k0 = ks * 32 + q * 8;
        bf16x8 aF[4];
        #pragma unroll
        for (int mt = 0; mt < 4; ++mt)
            aF[mt] = *(const bf16x8*)&sB[(mt * 16 + m) * LDB + k0];
        bf16x8 bF[2];
        #pragma unroll
        for (int nt = 0; nt < 2; ++nt) {
            int n = (wave << 5) + (nt << 4) + m;
            bF[nt] = *(const bf16x8*)&WLT[n * 128 + k0];
        }
        #pragma unroll
        for (int mt = 0; mt < 4; ++mt)
            #pragma unroll
            for (int nt = 0; nt < 2; ++nt)
                acc2[mt][nt] = __builtin_amdgcn_mfma_f32_16x16x32_bf16(
                    aF[mt], bF[nt], acc2[mt][nt], 0, 0, 0);
    }

    #pragma unroll
    for (int mt = 0; mt < 4; ++mt) {
        #pragma unroll
        for (int nt = 0; nt < 2; ++nt) {
            int col = (wave << 5) + (nt << 4) + m;
            #pragma unroll
            for (int i = 0; i < 4; ++i) {
                int rr = (mt << 4) + (q << 2) + i;
                if (e0 + rr < E) {
                    float v = acc2[mt][nt][i];
                    eo[(size_t)(e0 + rr) * H + col] = v > 0.f ? v : 0.f;
                }
            }
        }
    }
}

// ---------------- node aggregation: lvl[n] = sum of h over incident edges ----
// one wave per node; half-wave per edge (2 edges/iter), 8B/lane, unroll 2.
__global__ __launch_bounds__(256) void node_aggr_bf16(
    const uint2* __restrict__ hbuf8, const int* __restrict__ csr,
    const int* __restrict__ row_start, float* __restrict__ lvl, int N)
{
    const int wid = threadIdx.x >> 6, lane = threadIdx.x & 63;
    const int n = blockIdx.x * 4 + wid;
    if (n >= N) return;
    const int half = lane >> 5, li = lane & 31;   // lane covers cols li*4..li*4+3
    const int beg = row_start[n], end = row_start[n + 1];
    float a0 = 0.f, a1 = 0.f, a2 = 0.f, a3 = 0.f;

    int i = beg;
    for (; i + 4 <= end; i += 4) {
        int eA = csr[i + half], eB = csr[i + 2 + half];
        uint2 vA = hbuf8[(size_t)eA * 32 + li];
        uint2 vB = hbuf8[(size_t)eB * 32 + li];
        a0 += bf2f((short)(vA.x & 0xffff)) + bf2f((short)(vB.x & 0xffff));
        a1 += bf2f((short)(vA.x >> 16))    + bf2f((short)(vB.x >> 16));
        a2 += bf2f((short)(vA.y & 0xffff)) + bf2f((short)(vB.y & 0xffff));
        a3 += bf2f((short)(vA.y >> 16))    + bf2f((short)(vB.y >> 16));
    }
    if (i + 2 <= end) {
        int eA = csr[i + half];
        uint2 vA = hbuf8[(size_t)eA * 32 + li];
        a0 += bf2f((short)(vA.x & 0xffff));
        a1 += bf2f((short)(vA.x >> 16));
        a2 += bf2f((short)(vA.y & 0xffff));
        a3 += bf2f((short)(vA.y >> 16));
        i += 2;
    }
    if (i < end && half == 0) {
        int eA = csr[i];
        uint2 vA = hbuf8[(size_t)eA * 32 + li];
        a0 += bf2f((short)(vA.x & 0xffff));
        a1 += bf2f((short)(vA.x >> 16));
        a2 += bf2f((short)(vA.y & 0xffff));
        a3 += bf2f((short)(vA.y >> 16));
    }
    a0 += __shfl_xor(a0, 32);
    a1 += __shfl_xor(a1, 32);
    a2 += __shfl_xor(a2, 32);
    a3 += __shfl_xor(a3, 32);
    if (half == 0) {
        float4 out; out.x = a0; out.y = a1; out.z = a2; out.w = a3;
        *(float4*)(lvl + (size_t)n * H + li * 4) = out;
    }
}

__global__ __launch_bounds__(256) void node_aggr_f32(
    const float* __restrict__ hbuf, const int* __restrict__ csr,
    const int* __restrict__ row_start, float* __restrict__ lvl, int N)
{
    const int wid = threadIdx.x >> 6, lane = threadIdx.x & 63;
    const int n = blockIdx.x * 4 + wid;
    if (n >= N) return;
    const int beg = row_start[n], end = row_start[n + 1];
    float a0 = 0.f, a1 = 0.f;
    int i = beg;
    for (; i + 4 <= end; i += 4) {
        int e0 = csr[i], e1 = csr[i + 1], e2 = csr[i + 2], e3 = csr[i + 3];
        float2 v0 = *(const float2*)(hbuf + (size_t)e0 * H + 2 * lane);
        float2 v1 = *(const float2*)(hbuf + (size_t)e1 * H + 2 * lane);
        float2 v2 = *(const float2*)(hbuf + (size_t)e2 * H + 2 * lane);
        float2 v3 = *(const float2*)(hbuf + (size_t)e3 * H + 2 * lane);
        a0 += (v0.x + v1.x) + (v2.x + v3.x);
        a1 += (v0.y + v1.y) + (v2.y + v3.y);
    }
    for (; i < end; ++i) {
        int e = csr[i];
        float2 v = *(const float2*)(hbuf + (size_t)e * H + 2 * lane);
        a0 += v.x; a1 += v.y;
    }
    float2 out; out.x = a0; out.y = a1;
    *(float2*)(lvl + (size_t)n * H + 2 * lane) = out;
}

// ---------------- LEGACY edge kernel (atomic scatter) -- tiny-ws fallback ----
__global__ __launch_bounds__(256) void edge_kernel(
    const float* __restrict__ node_rep, const float* __restrict__ edge_rep,
    const int* __restrict__ eidx,
    const short* __restrict__ W1T, const short* __restrict__ WLT,
    const float* __restrict__ eps2p,
    float* __restrict__ lvl, float* __restrict__ edge_out, int E)
{
    __shared__ short sA[MB * LDA];
    __shared__ short sB[MB * LDB];
    __shared__ int sSrc[MB], sDst[MB];

    const int tid = threadIdx.x;
    const int e0  = blockIdx.x * MB;
    const float e2 = 1.f + eps2p[0];
    {
        int row  = tid >> 2;
        int cseg = (tid & 3) << 5;
        int e = e0 + row;
        int sIdx = 0, dIdx = 0;
        bool ev = (e < E);
        if (ev) { sIdx = eidx[e]; dIdx = eidx[E + e]; }
        if ((tid & 3) == 0) { sSrc[row] = sIdx; sDst[row] = dIdx; }
        short* rowA = sA + row * LDA;
        if (ev) {
            const float4* sp = (const float4*)(node_rep + (size_t)sIdx * H + cseg);
            const float4* dp = (const float4*)(node_rep + (size_t)dIdx * H + cseg);
            const float4* ep = (const float4*)(edge_rep + (size_t)e * H + cseg);
            #pragma unroll
            for (int j = 0; j < 8; ++j) {
                float4 a = sp[j], b = dp[j], c = ep[j];
                int cc = cseg + 4 * j;
                s16x4 lift = { f2bf(a.x + b.x), f2bf(a.y + b.y),
                               f2bf(a.z + b.z), f2bf(a.w + b.w) };
                s16x4 er   = { f2bf(c.x), f2bf(c.y), f2bf(c.z), f2bf(c.w) };
                *(s16x4*)&rowA[cc]      = lift;
                *(s16x4*)&rowA[H + cc]  = er;
            }
        } else {
            s16x4 z = {0, 0, 0, 0};
            #pragma unroll
            for (int j = 0; j < 8; ++j) {
                int cc = cseg + 4 * j;
                *(s16x4*)&rowA[cc]     = z;
                *(s16x4*)&rowA[H + cc] = z;
            }
        }
    }
    __syncthreads();

    const int wave = tid >> 6;
    const int lane = tid & 63;
    const int m = lane & 15;
    const int q = lane >> 4;

    f32x4 zero = {0.f, 0.f, 0.f, 0.f};
    f32x4 acc[4][2];
    #pragma unroll
    for (int mt = 0; mt < 4; ++mt)
        #pragma unroll
        for (int nt = 0; nt < 2; ++nt) acc[mt][nt] = zero;

    #pragma unroll
    for (int ks = 0; ks < 8; ++ks) {
        int k0 = ks * 32 + q * 8;
        bf16x8 aF[4];
        #pragma unroll
        for (int mt = 0; mt < 4; ++mt)
            aF[mt] = *(const bf16x8*)&sA[(mt * 16 + m) * LDA + k0];
        bf16x8 bF[2];
        #pragma unroll
        for (int nt = 0; nt < 2; ++nt) {
            int n = (wave << 5) + (nt << 4) + m;
            bF[nt] = *(const bf16x8*)&W1T[n * 256 + k0];
        }
        #pragma unroll
        for (int mt = 0; mt < 4; ++mt)
            #pragma unroll
            for (int nt = 0; nt < 2; ++nt)
                acc[mt][nt] = __builtin_amdgcn_mfma_f32_16x16x32_bf16(
                    aF[mt], bF[nt], acc[mt][nt], 0, 0, 0);
    }

    #pragma unroll
    for (int mt = 0; mt < 4; ++mt) {
        #pragma unroll
        for (int nt = 0; nt < 2; ++nt) {
            int col = (wave << 5) + (nt << 4) + m;
            #pragma unroll
            for (int i = 0; i < 4; ++i) {
                int rr = (mt << 4) + (q << 2) + i;
                if (e0 + rr < E) {
                    float h = acc[mt][nt][i];
                    h = h > 0.f ? h : 0.f;
                    int sn = sSrc[rr], dn = sDst[rr];
                    atomicAdd(lvl + (size_t)sn * H + col, h);
                    atomicAdd(lvl + (size_t)dn * H + col, h);
                    float b2 = e2 * h + bf2f(sA[rr * LDA + col]);
                    sB[rr * LDB + col] = f2bf(b2);
                }
            }
        }
    }
    __syncthreads();

    f32x4 acc2[4][2];
    #pragma unroll
    for (int mt = 0; mt < 4; ++mt)
        #pragma unroll
        for (int nt = 0; nt < 2; ++nt) acc2[mt][nt] = zero;

    #pragma unroll
    for (int ks = 0; ks < 4; ++ks) {
        int k0 = ks * 32 + q * 8;
        bf16x8 aF[4];
        #pragma unroll
        for (int mt = 0; mt < 4; ++mt)
            aF[mt] = *(const bf16x8*)&sB[(mt * 16 + m) * LDB + k0];
        bf16x8 bF[2];
        #pragma unroll
        for (int nt = 0; nt < 2; ++nt) {
            int n = (wave << 5) + (nt << 4) + m;
            bF[nt] = *(const bf16x8*)&WLT[n * 128 + k0];
        }
        #pragma unroll
        for (int mt = 0; mt < 4; ++mt)
            #pragma unroll
            for (int nt = 0; nt < 2; ++nt)
                acc2[mt][nt] = __builtin_amdgcn_mfma_f32_16x16x32_bf16(
                    aF[mt], bF[nt], acc2[mt][nt], 0, 0, 0);
    }

    #pragma unroll
    for (int mt = 0; mt < 4; ++mt) {
        #pragma unroll
        for (int nt = 0; nt < 2; ++nt) {
            int col = (wave << 5) + (nt << 4) + m;
            #pragma unroll
            for (int i = 0; i < 4; ++i) {
                int rr = (mt << 4) + (q << 2) + i;
                if (e0 + rr < E) {
                    float v = acc2[mt][nt][i];
                    edge_out[(size_t)(e0 + rr) * H + col] = v > 0.f ? v : 0.f;
                }
            }
        }
    }
}

// ---------------- node kernel ----------------
// node_out = relu(((1+eps1)*node_rep + lvl) @ W2); lvl may alias node_out.
__global__ __launch_bounds__(256) void node_kernel(
    const float* __restrict__ node_rep, const float* __restrict__ lvl,
    const short* __restrict__ W2T, const float* __restrict__ eps1p,
    float* __restrict__ node_out, int N)
{
    __shared__ short sA[MB * LDB];

    const int tid = threadIdx.x;
    const int r0  = blockIdx.x * MB;
    const float e1 = 1.f + eps1p[0];

    {
        int row  = tid >> 2;
        int cseg = (tid & 3) << 5;
        int r = r0 + row;
        short* rowA = sA + row * LDB;
        if (r < N) {
            const float4* np = (const float4*)(node_rep + (size_t)r * H + cseg);
            const float4* lp = (const float4*)(lvl + (size_t)r * H + cseg);
            #pragma unroll
            for (int j = 0; j < 8; ++j) {
                float4 a = np[j], b = lp[j];
                int cc = cseg + 4 * j;
                s16x4 v = { f2bf(e1 * a.x + b.x), f2bf(e1 * a.y + b.y),
                            f2bf(e1 * a.z + b.z), f2bf(e1 * a.w + b.w) };
                *(s16x4*)&rowA[cc] = v;
            }
        } else {
            s16x4 z = {0, 0, 0, 0};
            #pragma unroll
            for (int j = 0; j < 8; ++j) *(s16x4*)&rowA[cseg + 4 * j] = z;
        }
    }
    __syncthreads();

    const int wave = tid >> 6;
    const int lane = tid & 63;
    const int m = lane & 15;
    const int q = lane >> 4;

    f32x4 zero = {0.f, 0.f, 0.f, 0.f};
    f32x4 acc[4][2];
    #pragma unroll
    for (int mt = 0; mt < 4; ++mt)
        #pragma unroll
        for (int nt = 0; nt < 2; ++nt) acc[mt][nt] = zero;

    #pragma unroll
    for (int ks = 0; ks < 4; ++ks) {
        int k0 = ks * 32 + q * 8;
        bf16x8 aF[4];
        #pragma unroll
        for (int mt = 0; mt < 4; ++mt)
            aF[mt] = *(const bf16x8*)&sA[(mt * 16 + m) * LDB + k0];
        bf16x8 bF[2];
        #pragma unroll
        for (int nt = 0; nt < 2; ++nt) {
            int n = (wave << 5) + (nt << 4) + m;
            bF[nt] = *(const bf16x8*)&W2T[n * 128 + k0];
        }
        #pragma unroll
        for (int mt = 0; mt < 4; ++mt)
            #pragma unroll
            for (int nt = 0; nt < 2; ++nt)
                acc[mt][nt] = __builtin_amdgcn_mfma_f32_16x16x32_bf16(
                    aF[mt], bF[nt], acc[mt][nt], 0, 0, 0);
    }

    #pragma unroll
    for (int mt = 0; mt < 4; ++mt) {
        #pragma unroll
        for (int nt = 0; nt < 2; ++nt) {
            int col = (wave << 5) + (nt << 4) + m;
            #pragma unroll
            for (int i = 0; i < 4; ++i) {
                int rr = (mt << 4) + (q << 2) + i;
                if (r0 + rr < N) {
                    float v = acc[mt][nt][i];
                    node_out[(size_t)(r0 + rr) * H + col] = v > 0.f ? v : 0.f;
                }
            }
        }
    }
}

static inline size_t algn(size_t x) { return (x + 255) & ~(size_t)255; }

extern "C" void kernel_launch(void* const* d_in, const int* in_sizes, int n_in,
                              void* d_out, int out_size, void* d_ws, size_t ws_size,
                              hipStream_t stream) {
    const float* node_rep = (const float*)d_in[0];
    const float* edge_rep = (const float*)d_in[1];
    const int*   eidx     = (const int*)d_in[2];
    const float* W1       = (const float*)d_in[3];
    const float* W2       = (const float*)d_in[4];
    const float* WL       = (const float*)d_in[5];
    const float* eps1     = (const float*)d_in[6];
    const float* eps2     = (const float*)d_in[7];

    const int N = in_sizes[0] / H;     // 50000
    const int E = in_sizes[1] / H;     // 800000

    float* node_out = (float*)d_out;
    float* edge_out = (float*)d_out + (size_t)N * H;
    float* lvl = node_out;             // lvl aliases node_out (node_kernel is in-place safe)

    char* ws = (char*)d_ws;
    short* W1T = (short*)ws;                       // 64 KB
    short* W2T = (short*)(ws + 65536);             // 32 KB
    short* WLT = (short*)(ws + 65536 + 32768);     // 32 KB
    size_t off = 131072;

    int* deg       = (int*)(ws + off); off += algn((size_t)N * 4);
    int* row_start = (int*)(ws + off); off += algn((size_t)(N + 1) * 4);
    int* cursor    = (int*)(ws + off); off += algn((size_t)N * 4);
    int* csr       = (int*)(ws + off); off += algn((size_t)2 * E * 4);
    const size_t need_small = off;
    short* hbuf    = (short*)(ws + off); off += algn((size_t)E * H * sizeof(short));
    const size_t need_big = off;
    short* nodeB   = (short*)(ws + off); off += algn((size_t)N * H * sizeof(short));
    const size_t need_nb = off;

    prep_weights<<<128, 256, 0, stream>>>(W1, W2, WL, W1T, W2T, WLT);

    const int twoE = 2 * E;
    const int egrid = (E + MB - 1) / MB;
    const int ngrid = (N + MB - 1) / MB;

    if (ws_size >= need_small) {
        // build CSR incidence lists (int atomics only: 2E ops)
        hipMemsetAsync(deg, 0, (size_t)N * 4, stream);
        count_deg<<<(twoE + 255) / 256, 256, 0, stream>>>(eidx, deg, twoE);
        scan_deg<<<1, 1024, 0, stream>>>(deg, row_start, cursor, N);
        fill_csr<<<(twoE + 255) / 256, 256, 0, stream>>>(eidx, cursor, csr, E);

        if (ws_size >= need_big) {
            if (ws_size >= need_nb) {
                int total8 = (N * H) / 8;
                prep_nodes<<<(total8 + 255) / 256, 256, 0, stream>>>(
                    node_rep, nodeB, total8);
                int tiles = (E + 15) / 16;
                int wgrid = (tiles + 3) / 4;
                edge_wave<<<wgrid, 256, 0, stream>>>(
                    nodeB, edge_rep, eidx, W1T, WLT, eps2, hbuf, edge_out, E);
            } else {
                edge_fused_nb<<<egrid, 256, 0, stream>>>(
                    node_rep, edge_rep, eidx, W1T, WLT, eps2, hbuf, edge_out, E);
            }
            node_aggr_bf16<<<(N + 3) / 4, 256, 0, stream>>>(
                (const uint2*)hbuf, csr, row_start, lvl, N);
            node_kernel<<<ngrid, 256, 0, stream>>>(
                node_rep, lvl, W2T, eps1, node_out, N);
        } else {
            // PATH B: h f32 transits through edge_out region
            edge_h_kernel<<<egrid, 256, 0, stream>>>(
                node_rep, edge_rep, eidx, W1T, edge_out, E);
            node_aggr_f32<<<(N + 3) / 4, 256, 0, stream>>>(
                edge_out, csr, row_start, lvl, N);
            node_kernel<<<ngrid, 256, 0, stream>>>(
                node_rep, lvl, W2T, eps1, node_out, N);
            edge_finalize<<<egrid, 256, 0, stream>>>(
                node_rep, eidx, WLT, eps2, edge_out, E);
        }
    } else {
        // LEGACY: atomic scatter
        hipMemsetAsync(lvl, 0, (size_t)N * H * sizeof(float), stream);
        edge_kernel<<<egrid, 256, 0, stream>>>(
            node_rep, edge_rep, eidx, W1T, WLT, eps2, lvl, edge_out, E);
        node_kernel<<<ngrid, 256, 0, stream>>>(
            node_rep, lvl, W2T, eps1, node_out, N);
    }
}

// Round 4
// 1539.853 us; speedup vs baseline: 1.0858x; 1.0858x over previous
//
#include <hip/hip_runtime.h>

#define H 128
#define MB 64          // edges (or nodes) per block
#define TPB 4          // tiles per block in edge_pipe
#define LDA 264        // LDS row stride (elems) for the [64 x 256] concat tile (+8 pad)
#define LDB 136        // LDS row stride for [64 x 128] tiles (+8 pad)

typedef __attribute__((ext_vector_type(8))) short bf16x8;
typedef __attribute__((ext_vector_type(4))) short s16x4;
typedef __attribute__((ext_vector_type(4))) float f32x4;

__device__ __forceinline__ short f2bf(float f) {
    union { float f; unsigned u; } v; v.f = f;
    unsigned r = v.u + 0x7FFF + ((v.u >> 16) & 1);   // RTNE
    return (short)(r >> 16);
}
__device__ __forceinline__ float bf2f(short s) {
    union { unsigned u; float f; } v;
    v.u = ((unsigned)(unsigned short)s) << 16;
    return v.f;
}

// ---------------- weight prep: fp32 [K,N] -> bf16 transposed [N,K] ----------------
__global__ __launch_bounds__(256) void prep_weights(
    const float* __restrict__ W1, const float* __restrict__ W2,
    const float* __restrict__ WL,
    short* __restrict__ W1T, short* __restrict__ W2T, short* __restrict__ WLT)
{
    int tid = blockIdx.x * 256 + threadIdx.x;      // 0..32767
    {   // W1: [256,128] -> W1T [128][256]
        int n = tid >> 8, k = tid & 255;
        W1T[n * 256 + k] = f2bf(W1[k * 128 + n]);
    }
    if (tid < 16384) {  // W2, W_lift: [128,128] -> [128][128]
        int n = tid >> 7, k = tid & 127;
        W2T[n * 128 + k] = f2bf(W2[k * 128 + n]);
        WLT[n * 128 + k] = f2bf(WL[k * 128 + n]);
    }
}

// node_rep fp32 -> bf16 copy (halves the gather bytes in the edge kernel)
__global__ __launch_bounds__(256) void prep_nodes(
    const float* __restrict__ nr, short* __restrict__ nodeB, int total8)
{
    int t = blockIdx.x * 256 + threadIdx.x;
    if (t >= total8) return;
    const float4* p = (const float4*)nr + (size_t)t * 2;
    float4 a = p[0], b = p[1];
    bf16x8 v = { f2bf(a.x), f2bf(a.y), f2bf(a.z), f2bf(a.w),
                 f2bf(b.x), f2bf(b.y), f2bf(b.z), f2bf(b.w) };
    *(bf16x8*)(nodeB + (size_t)t * 8) = v;
}

// ---------------- CSR build ----------------
__global__ __launch_bounds__(256) void count_deg(
    const int* __restrict__ eidx, int* __restrict__ deg, int twoE)
{
    int t = blockIdx.x * 256 + threadIdx.x;
    if (t < twoE) atomicAdd(&deg[eidx[t]], 1);
}

// single-block exclusive scan of deg[N] -> row_start[N+1] and cursor[N]
__global__ __launch_bounds__(1024) void scan_deg(
    const int* __restrict__ deg, int* __restrict__ row_start,
    int* __restrict__ cursor, int N)
{
    __shared__ int part[1024];
    const int t = threadIdx.x;
    const int chunk = (N + 1023) >> 10;
    const int b = t * chunk;
    const int e = (b + chunk < N) ? (b + chunk) : N;
    int s = 0;
    for (int j = b; j < e; ++j) s += deg[j];
    part[t] = s;
    __syncthreads();
    for (int off = 1; off < 1024; off <<= 1) {
        int v = part[t];
        int u = (t >= off) ? part[t - off] : 0;
        __syncthreads();
        part[t] = v + u;
        __syncthreads();
    }
    int run = (t == 0) ? 0 : part[t - 1];
    for (int j = b; j < e; ++j) {
        int d = deg[j];
        row_start[j] = run;
        cursor[j]    = run;
        run += d;
    }
    if (t == 1023) row_start[N] = part[1023];
}

__global__ __launch_bounds__(256) void fill_csr(
    const int* __restrict__ eidx, int* __restrict__ cursor,
    int* __restrict__ csr, int E)
{
    int t = blockIdx.x * 256 + threadIdx.x;
    if (t < 2 * E) {
        int node = eidx[t];
        int e = (t < E) ? t : (t - E);
        int pos = atomicAdd(&cursor[node], 1);
        csr[pos] = e;
    }
}

// ---------------- PATH A: pipelined fused edge kernel ----------------
// Block-tile (keeps per-wave W1T/WLT column slices L1-resident), but each block
// processes TPB consecutive tiles: the random nodeB gathers for tile t+1 are
// issued into registers right after tile t's stage barrier, completing under
// GEMM1+epilogue (~1500 cy) -- the vmcnt drain at the next barrier is free.
__global__ __launch_bounds__(256, 4) void edge_pipe(
    const short* __restrict__ nodeB, const float* __restrict__ edge_rep,
    const int* __restrict__ eidx,
    const short* __restrict__ W1T, const short* __restrict__ WLT,
    const float* __restrict__ eps2p,
    short* __restrict__ hbuf, float* __restrict__ edge_out,
    int E, int nTiles)
{
    __shared__ short sA[MB * LDA];   // concat(lift, edge_rep) bf16; lift half becomes b2

    const int tid  = threadIdx.x;
    const int row  = tid >> 2;          // 0..63
    const int cseg = (tid & 3) << 5;    // 0,32,64,96
    const int wave = tid >> 6;
    const int lane = tid & 63;
    const int m = lane & 15;            // A row / B col / D col
    const int q = lane >> 4;            // k-quad / D row group
    const float e2 = 1.f + eps2p[0];

    int t = blockIdx.x * TPB;
    if (t >= nTiles) return;
    const int tEnd = (t + TPB < nTiles) ? (t + TPB) : nTiles;

    // ---- prologue: gather tile t's node rows into registers ----
    bf16x8 pS[4], pD[4];
    bool pv;
    {
        int e = t * MB + row;
        pv = (e < E);
        if (pv) {
            int sIdx = eidx[e], dIdx = eidx[E + e];
            const bf16x8* sp = (const bf16x8*)(nodeB + (size_t)sIdx * H + cseg);
            const bf16x8* dp = (const bf16x8*)(nodeB + (size_t)dIdx * H + cseg);
            #pragma unroll
            for (int j = 0; j < 4; ++j) { pS[j] = sp[j]; pD[j] = dp[j]; }
        }
    }

    for (; t < tEnd; ++t) {
        const int e0 = t * MB;

        // ---- stage: lift from prefetched regs; edge_rep streamed ----
        {
            short* rowA = sA + row * LDA;
            if (pv) {
                const float4* ep = (const float4*)(edge_rep + (size_t)(e0 + row) * H + cseg);
                float4 ev[8];
                #pragma unroll
                for (int j = 0; j < 8; ++j) ev[j] = ep[j];
                #pragma unroll
                for (int j = 0; j < 4; ++j) {
                    bf16x8 lift;
                    #pragma unroll
                    for (int k = 0; k < 8; ++k)
                        lift[k] = f2bf(bf2f(pS[j][k]) + bf2f(pD[j][k]));
                    *(bf16x8*)&rowA[cseg + 8 * j] = lift;
                }
                #pragma unroll
                for (int j = 0; j < 8; ++j) {
                    float4 c = ev[j];
                    s16x4 er = { f2bf(c.x), f2bf(c.y), f2bf(c.z), f2bf(c.w) };
                    *(s16x4*)&rowA[H + cseg + 4 * j] = er;
                }
            } else {
                s16x4 z = {0, 0, 0, 0};
                #pragma unroll
                for (int j = 0; j < 8; ++j) {
                    int cc = cseg + 4 * j;
                    *(s16x4*)&rowA[cc]     = z;
                    *(s16x4*)&rowA[H + cc] = z;
                }
            }
        }
        __syncthreads();

        // ---- issue next tile's gathers (latency hidden under GEMM1+epilogue) ----
        if (t + 1 < tEnd) {
            int e = (t + 1) * MB + row;
            pv = (e < E);
            if (pv) {
                int sIdx = eidx[e], dIdx = eidx[E + e];
                const bf16x8* sp = (const bf16x8*)(nodeB + (size_t)sIdx * H + cseg);
                const bf16x8* dp = (const bf16x8*)(nodeB + (size_t)dIdx * H + cseg);
                #pragma unroll
                for (int j = 0; j < 4; ++j) { pS[j] = sp[j]; pD[j] = dp[j]; }
            }
        }

        // ---- GEMM1: [64,256] x [256,128] -> h ----
        f32x4 zero = {0.f, 0.f, 0.f, 0.f};
        f32x4 acc[4][2];
        #pragma unroll
        for (int mt = 0; mt < 4; ++mt)
            #pragma unroll
            for (int nt = 0; nt < 2; ++nt) acc[mt][nt] = zero;

        #pragma unroll
        for (int ks = 0; ks < 8; ++ks) {
            int k0 = ks * 32 + q * 8;
            bf16x8 aF[4];
            #pragma unroll
            for (int mt = 0; mt < 4; ++mt)
                aF[mt] = *(const bf16x8*)&sA[(mt * 16 + m) * LDA + k0];
            bf16x8 bF[2];
            #pragma unroll
            for (int nt = 0; nt < 2; ++nt) {
                int n = (wave << 5) + (nt << 4) + m;
                bF[nt] = *(const bf16x8*)&W1T[n * 256 + k0];
            }
            #pragma unroll
            for (int mt = 0; mt < 4; ++mt)
                #pragma unroll
                for (int nt = 0; nt < 2; ++nt)
                    acc[mt][nt] = __builtin_amdgcn_mfma_f32_16x16x32_bf16(
                        aF[mt], bF[nt], acc[mt][nt], 0, 0, 0);
        }
        __syncthreads();   // all waves done reading sA before in-place update

        // ---- epilogue: relu, store h bf16, b2 = e2*h + lift (LDS RMW) ----
        #pragma unroll
        for (int mt = 0; mt < 4; ++mt) {
            #pragma unroll
            for (int nt = 0; nt < 2; ++nt) {
                int col = (wave << 5) + (nt << 4) + m;
                #pragma unroll
                for (int i = 0; i < 4; ++i) {
                    int rr = (mt << 4) + (q << 2) + i;
                    if (e0 + rr < E) {
                        float h = acc[mt][nt][i];
                        h = h > 0.f ? h : 0.f;
                        hbuf[(size_t)(e0 + rr) * H + col] = f2bf(h);
                        float b2 = e2 * h + bf2f(sA[rr * LDA + col]);
                        sA[rr * LDA + col] = f2bf(b2);
                    }
                }
            }
        }
        __syncthreads();

        // ---- GEMM2: edge_out = relu(b2 @ W_lift) ----
        f32x4 acc2[4][2];
        #pragma unroll
        for (int mt = 0; mt < 4; ++mt)
            #pragma unroll
            for (int nt = 0; nt < 2; ++nt) acc2[mt][nt] = zero;

        #pragma unroll
        for (int ks = 0; ks < 4; ++ks) {
            int k0 = ks * 32 + q * 8;
            bf16x8 aF[4];
            #pragma unroll
            for (int mt = 0; mt < 4; ++mt)
                aF[mt] = *(const bf16x8*)&sA[(mt * 16 + m) * LDA + k0];
            bf16x8 bF[2];
            #pragma unroll
            for (int nt = 0; nt < 2; ++nt) {
                int n = (wave << 5) + (nt << 4) + m;
                bF[nt] = *(const bf16x8*)&WLT[n * 128 + k0];
            }
            #pragma unroll
            for (int mt = 0; mt < 4; ++mt)
                #pragma unroll
                for (int nt = 0; nt < 2; ++nt)
                    acc2[mt][nt] = __builtin_amdgcn_mfma_f32_16x16x32_bf16(
                        aF[mt], bF[nt], acc2[mt][nt], 0, 0, 0);
        }

        #pragma unroll
        for (int mt = 0; mt < 4; ++mt) {
            #pragma unroll
            for (int nt = 0; nt < 2; ++nt) {
                int col = (wave << 5) + (nt << 4) + m;
                #pragma unroll
                for (int i = 0; i < 4; ++i) {
                    int rr = (mt << 4) + (q << 2) + i;
                    if (e0 + rr < E) {
                        float v = acc2[mt][nt][i];
                        edge_out[(size_t)(e0 + rr) * H + col] = v > 0.f ? v : 0.f;
                    }
                }
            }
        }
        __syncthreads();   // GEMM2 reads done before next stage overwrites sA
    }
}

// ---------------- fallback fused edge kernel (block-tile, no nodeB) ----------
__global__ __launch_bounds__(256) void edge_fused_nb(
    const float* __restrict__ node_rep, const float* __restrict__ edge_rep,
    const int* __restrict__ eidx,
    const short* __restrict__ W1T, const short* __restrict__ WLT,
    const float* __restrict__ eps2p,
    short* __restrict__ hbuf, float* __restrict__ edge_out, int E)
{
    __shared__ short sA[MB * LDA];

    const int tid = threadIdx.x;
    const int e0  = blockIdx.x * MB;
    const float e2 = 1.f + eps2p[0];

    {
        int row  = tid >> 2;
        int cseg = (tid & 3) << 5;
        int e = e0 + row;
        short* rowA = sA + row * LDA;
        if (e < E) {
            int sIdx = eidx[e], dIdx = eidx[E + e];
            const float4* sp = (const float4*)(node_rep + (size_t)sIdx * H + cseg);
            const float4* dp = (const float4*)(node_rep + (size_t)dIdx * H + cseg);
            const float4* ep = (const float4*)(edge_rep + (size_t)e * H + cseg);
            #pragma unroll
            for (int j = 0; j < 8; ++j) {
                float4 a = sp[j], b = dp[j], c = ep[j];
                int cc = cseg + 4 * j;
                s16x4 lift = { f2bf(a.x + b.x), f2bf(a.y + b.y),
                               f2bf(a.z + b.z), f2bf(a.w + b.w) };
                s16x4 er   = { f2bf(c.x), f2bf(c.y), f2bf(c.z), f2bf(c.w) };
                *(s16x4*)&rowA[cc]      = lift;
                *(s16x4*)&rowA[H + cc]  = er;
            }
        } else {
            s16x4 z = {0, 0, 0, 0};
            #pragma unroll
            for (int j = 0; j < 8; ++j) {
                int cc = cseg + 4 * j;
                *(s16x4*)&rowA[cc]     = z;
                *(s16x4*)&rowA[H + cc] = z;
            }
        }
    }
    __syncthreads();

    const int wave = tid >> 6;
    const int lane = tid & 63;
    const int m = lane & 15;
    const int q = lane >> 4;

    f32x4 zero = {0.f, 0.f, 0.f, 0.f};
    f32x4 acc[4][2];
    #pragma unroll
    for (int mt = 0; mt < 4; ++mt)
        #pragma unroll
        for (int nt = 0; nt < 2; ++nt) acc[mt][nt] = zero;

    #pragma unroll
    for (int ks = 0; ks < 8; ++ks) {
        int k0 = ks * 32 + q * 8;
        bf16x8 aF[4];
        #pragma unroll
        for (int mt = 0; mt < 4; ++mt)
            aF[mt] = *(const bf16x8*)&sA[(mt * 16 + m) * LDA + k0];
        bf16x8 bF[2];
        #pragma unroll
        for (int nt = 0; nt < 2; ++nt) {
            int n = (wave << 5) + (nt << 4) + m;
            bF[nt] = *(const bf16x8*)&W1T[n * 256 + k0];
        }
        #pragma unroll
        for (int mt = 0; mt < 4; ++mt)
            #pragma unroll
            for (int nt = 0; nt < 2; ++nt)
                acc[mt][nt] = __builtin_amdgcn_mfma_f32_16x16x32_bf16(
                    aF[mt], bF[nt], acc[mt][nt], 0, 0, 0);
    }
    __syncthreads();

    #pragma unroll
    for (int mt = 0; mt < 4; ++mt) {
        #pragma unroll
        for (int nt = 0; nt < 2; ++nt) {
            int col = (wave << 5) + (nt << 4) + m;
            #pragma unroll
            for (int i = 0; i < 4; ++i) {
                int rr = (mt << 4) + (q << 2) + i;
                if (e0 + rr < E) {
                    float h = acc[mt][nt][i];
                    h = h > 0.f ? h : 0.f;
                    hbuf[(size_t)(e0 + rr) * H + col] = f2bf(h);
                    float b2 = e2 * h + bf2f(sA[rr * LDA + col]);
                    sA[rr * LDA + col] = f2bf(b2);
                }
            }
        }
    }
    __syncthreads();

    f32x4 acc2[4][2];
    #pragma unroll
    for (int mt = 0; mt < 4; ++mt)
        #pragma unroll
        for (int nt = 0; nt < 2; ++nt) acc2[mt][nt] = zero;

    #pragma unroll
    for (int ks = 0; ks < 4; ++ks) {
        int k0 = ks * 32 + q * 8;
        bf16x8 aF[4];
        #pragma unroll
        for (int mt = 0; mt < 4; ++mt)
            aF[mt] = *(const bf16x8*)&sA[(mt * 16 + m) * LDA + k0];
        bf16x8 bF[2];
        #pragma unroll
        for (int nt = 0; nt < 2; ++nt) {
            int n = (wave << 5) + (nt << 4) + m;
            bF[nt] = *(const bf16x8*)&WLT[n * 128 + k0];
        }
        #pragma unroll
        for (int mt = 0; mt < 4; ++mt)
            #pragma unroll
            for (int nt = 0; nt < 2; ++nt)
                acc2[mt][nt] = __builtin_amdgcn_mfma_f32_16x16x32_bf16(
                    aF[mt], bF[nt], acc2[mt][nt], 0, 0, 0);
    }

    #pragma unroll
    for (int mt = 0; mt < 4; ++mt) {
        #pragma unroll
        for (int nt = 0; nt < 2; ++nt) {
            int col = (wave << 5) + (nt << 4) + m;
            #pragma unroll
            for (int i = 0; i < 4; ++i) {
                int rr = (mt << 4) + (q << 2) + i;
                if (e0 + rr < E) {
                    float v = acc2[mt][nt][i];
                    edge_out[(size_t)(e0 + rr) * H + col] = v > 0.f ? v : 0.f;
                }
            }
        }
    }
}

// ---------------- PATH B: split edge kernels, h transits f32 via edge_out ----
__global__ __launch_bounds__(256) void edge_h_kernel(
    const float* __restrict__ node_rep, const float* __restrict__ edge_rep,
    const int* __restrict__ eidx, const short* __restrict__ W1T,
    float* __restrict__ hbuf, int E)
{
    __shared__ short sA[MB * LDA];
    const int tid = threadIdx.x;
    const int e0  = blockIdx.x * MB;
    {
        int row  = tid >> 2;
        int cseg = (tid & 3) << 5;
        int e = e0 + row;
        short* rowA = sA + row * LDA;
        if (e < E) {
            int sIdx = eidx[e], dIdx = eidx[E + e];
            const float4* sp = (const float4*)(node_rep + (size_t)sIdx * H + cseg);
            const float4* dp = (const float4*)(node_rep + (size_t)dIdx * H + cseg);
            const float4* ep = (const float4*)(edge_rep + (size_t)e * H + cseg);
            #pragma unroll
            for (int j = 0; j < 8; ++j) {
                float4 a = sp[j], b = dp[j], c = ep[j];
                int cc = cseg + 4 * j;
                s16x4 lift = { f2bf(a.x + b.x), f2bf(a.y + b.y),
                               f2bf(a.z + b.z), f2bf(a.w + b.w) };
                s16x4 er   = { f2bf(c.x), f2bf(c.y), f2bf(c.z), f2bf(c.w) };
                *(s16x4*)&rowA[cc]      = lift;
                *(s16x4*)&rowA[H + cc]  = er;
            }
        } else {
            s16x4 z = {0, 0, 0, 0};
            #pragma unroll
            for (int j = 0; j < 8; ++j) {
                int cc = cseg + 4 * j;
                *(s16x4*)&rowA[cc]     = z;
                *(s16x4*)&rowA[H + cc] = z;
            }
        }
    }
    __syncthreads();

    const int wave = tid >> 6;
    const int lane = tid & 63;
    const int m = lane & 15;
    const int q = lane >> 4;

    f32x4 zero = {0.f, 0.f, 0.f, 0.f};
    f32x4 acc[4][2];
    #pragma unroll
    for (int mt = 0; mt < 4; ++mt)
        #pragma unroll
        for (int nt = 0; nt < 2; ++nt) acc[mt][nt] = zero;

    #pragma unroll
    for (int ks = 0; ks < 8; ++ks) {
        int k0 = ks * 32 + q * 8;
        bf16x8 aF[4];
        #pragma unroll
        for (int mt = 0; mt < 4; ++mt)
            aF[mt] = *(const bf16x8*)&sA[(mt * 16 + m) * LDA + k0];
        bf16x8 bF[2];
        #pragma unroll
        for (int nt = 0; nt < 2; ++nt) {
            int n = (wave << 5) + (nt << 4) + m;
            bF[nt] = *(const bf16x8*)&W1T[n * 256 + k0];
        }
        #pragma unroll
        for (int mt = 0; mt < 4; ++mt)
            #pragma unroll
            for (int nt = 0; nt < 2; ++nt)
                acc[mt][nt] = __builtin_amdgcn_mfma_f32_16x16x32_bf16(
                    aF[mt], bF[nt], acc[mt][nt], 0, 0, 0);
    }

    #pragma unroll
    for (int mt = 0; mt < 4; ++mt) {
        #pragma unroll
        for (int nt = 0; nt < 2; ++nt) {
            int col = (wave << 5) + (nt << 4) + m;
            #pragma unroll
            for (int i = 0; i < 4; ++i) {
                int rr = (mt << 4) + (q << 2) + i;
                if (e0 + rr < E) {
                    float h = acc[mt][nt][i];
                    hbuf[(size_t)(e0 + rr) * H + col] = h > 0.f ? h : 0.f;
                }
            }
        }
    }
}

// finalize: edge_out = relu((e2*h + lift) @ W_lift); h f32 read from eo, written in place
__global__ __launch_bounds__(256) void edge_finalize(
    const float* __restrict__ node_rep, const int* __restrict__ eidx,
    const short* __restrict__ WLT, const float* __restrict__ eps2p,
    float* __restrict__ eo, int E)
{
    __shared__ short sB[MB * LDB];
    const int tid = threadIdx.x;
    const int e0  = blockIdx.x * MB;
    const float e2 = 1.f + eps2p[0];
    {
        int row  = tid >> 2;
        int cseg = (tid & 3) << 5;
        int e = e0 + row;
        short* rowB = sB + row * LDB;
        if (e < E) {
            int sIdx = eidx[e], dIdx = eidx[E + e];
            const float4* hp = (const float4*)(eo + (size_t)e * H + cseg);
            const float4* sp = (const float4*)(node_rep + (size_t)sIdx * H + cseg);
            const float4* dp = (const float4*)(node_rep + (size_t)dIdx * H + cseg);
            #pragma unroll
            for (int j = 0; j < 8; ++j) {
                float4 hv = hp[j], a = sp[j], b = dp[j];
                int cc = cseg + 4 * j;
                s16x4 v = { f2bf(e2 * hv.x + a.x + b.x), f2bf(e2 * hv.y + a.y + b.y),
                            f2bf(e2 * hv.z + a.z + b.z), f2bf(e2 * hv.w + a.w + b.w) };
                *(s16x4*)&rowB[cc] = v;
            }
        } else {
            s16x4 z = {0, 0, 0, 0};
            #pragma unroll
            for (int j = 0; j < 8; ++j) *(s16x4*)&rowB[cseg + 4 * j] = z;
        }
    }
    __syncthreads();

    const int wave = tid >> 6;
    const int lane = tid & 63;
    const int m = lane & 15;
    const int q = lane >> 4;

    f32x4 zero = {0.f, 0.f, 0.f, 0.f};
    f32x4 acc2[4][2];
    #pragma unroll
    for (int mt = 0; mt < 4; ++mt)
        #pragma unroll
        for (int nt = 0; nt < 2; ++nt) acc2[mt][nt] = zero;

    #pragma unroll
    for (int ks = 0; ks < 4; ++ks) {
        int k0 = ks * 32 + q * 8;
        bf16x8 aF[4];
        #pragma unroll
        for (int mt = 0; mt < 4; ++mt)
            aF[mt] = *(const bf16x8*)&sB[(mt * 16 + m) * LDB + k0];
        bf16x8 bF[2];
        #pragma unroll
        for (int nt = 0; nt < 2; ++nt) {
            int n = (wave << 5) + (nt << 4) + m;
            bF[nt] = *(const bf16x8*)&WLT[n * 128 + k0];
        }
        #pragma unroll
        for (int mt = 0; mt < 4; ++mt)
            #pragma unroll
            for (int nt = 0; nt < 2; ++nt)
                acc2[mt][nt] = __builtin_amdgcn_mfma_f32_16x16x32_bf16(
                    aF[mt], bF[nt], acc2[mt][nt], 0, 0, 0);
    }

    #pragma unroll
    for (int mt = 0; mt < 4; ++mt) {
        #pragma unroll
        for (int nt = 0; nt < 2; ++nt) {
            int col = (wave << 5) + (nt << 4) + m;
            #pragma unroll
            for (int i = 0; i < 4; ++i) {
                int rr = (mt << 4) + (q << 2) + i;
                if (e0 + rr < E) {
                    float v = acc2[mt][nt][i];
                    eo[(size_t)(e0 + rr) * H + col] = v > 0.f ? v : 0.f;
                }
            }
        }
    }
}

// ---------------- node aggregation: lvl[n] = sum of h over incident edges ----
// one wave per node; half-wave per edge (2 edges/iter), 8B/lane, unroll 2.
__global__ __launch_bounds__(256) void node_aggr_bf16(
    const uint2* __restrict__ hbuf8, const int* __restrict__ csr,
    const int* __restrict__ row_start, float* __restrict__ lvl, int N)
{
    const int wid = threadIdx.x >> 6, lane = threadIdx.x & 63;
    const int n = blockIdx.x * 4 + wid;
    if (n >= N) return;
    const int half = lane >> 5, li = lane & 31;   // lane covers cols li*4..li*4+3
    const int beg = row_start[n], end = row_start[n + 1];
    float a0 = 0.f, a1 = 0.f, a2 = 0.f, a3 = 0.f;

    int i = beg;
    for (; i + 4 <= end; i += 4) {
        int eA = csr[i + half], eB = csr[i + 2 + half];
        uint2 vA = hbuf8[(size_t)eA * 32 + li];
        uint2 vB = hbuf8[(size_t)eB * 32 + li];
        a0 += bf2f((short)(vA.x & 0xffff)) + bf2f((short)(vB.x & 0xffff));
        a1 += bf2f((short)(vA.x >> 16))    + bf2f((short)(vB.x >> 16));
        a2 += bf2f((short)(vA.y & 0xffff)) + bf2f((short)(vB.y & 0xffff));
        a3 += bf2f((short)(vA.y >> 16))    + bf2f((short)(vB.y >> 16));
    }
    if (i + 2 <= end) {
        int eA = csr[i + half];
        uint2 vA = hbuf8[(size_t)eA * 32 + li];
        a0 += bf2f((short)(vA.x & 0xffff));
        a1 += bf2f((short)(vA.x >> 16));
        a2 += bf2f((short)(vA.y & 0xffff));
        a3 += bf2f((short)(vA.y >> 16));
        i += 2;
    }
    if (i < end && half == 0) {
        int eA = csr[i];
        uint2 vA = hbuf8[(size_t)eA * 32 + li];
        a0 += bf2f((short)(vA.x & 0xffff));
        a1 += bf2f((short)(vA.x >> 16));
        a2 += bf2f((short)(vA.y & 0xffff));
        a3 += bf2f((short)(vA.y >> 16));
    }
    a0 += __shfl_xor(a0, 32);
    a1 += __shfl_xor(a1, 32);
    a2 += __shfl_xor(a2, 32);
    a3 += __shfl_xor(a3, 32);
    if (half == 0) {
        float4 out; out.x = a0; out.y = a1; out.z = a2; out.w = a3;
        *(float4*)(lvl + (size_t)n * H + li * 4) = out;
    }
}

__global__ __launch_bounds__(256) void node_aggr_f32(
    const float* __restrict__ hbuf, const int* __restrict__ csr,
    const int* __restrict__ row_start, float* __restrict__ lvl, int N)
{
    const int wid = threadIdx.x >> 6, lane = threadIdx.x & 63;
    const int n = blockIdx.x * 4 + wid;
    if (n >= N) return;
    const int beg = row_start[n], end = row_start[n + 1];
    float a0 = 0.f, a1 = 0.f;
    int i = beg;
    for (; i + 4 <= end; i += 4) {
        int e0 = csr[i], e1 = csr[i + 1], e2 = csr[i + 2], e3 = csr[i + 3];
        float2 v0 = *(const float2*)(hbuf + (size_t)e0 * H + 2 * lane);
        float2 v1 = *(const float2*)(hbuf + (size_t)e1 * H + 2 * lane);
        float2 v2 = *(const float2*)(hbuf + (size_t)e2 * H + 2 * lane);
        float2 v3 = *(const float2*)(hbuf + (size_t)e3 * H + 2 * lane);
        a0 += (v0.x + v1.x) + (v2.x + v3.x);
        a1 += (v0.y + v1.y) + (v2.y + v3.y);
    }
    for (; i < end; ++i) {
        int e = csr[i];
        float2 v = *(const float2*)(hbuf + (size_t)e * H + 2 * lane);
        a0 += v.x; a1 += v.y;
    }
    float2 out; out.x = a0; out.y = a1;
    *(float2*)(lvl + (size_t)n * H + 2 * lane) = out;
}

// ---------------- LEGACY edge kernel (atomic scatter) -- tiny-ws fallback ----
__global__ __launch_bounds__(256) void edge_kernel(
    const float* __restrict__ node_rep, const float* __restrict__ edge_rep,
    const int* __restrict__ eidx,
    const short* __restrict__ W1T, const short* __restrict__ WLT,
    const float* __restrict__ eps2p,
    float* __restrict__ lvl, float* __restrict__ edge_out, int E)
{
    __shared__ short sA[MB * LDA];
    __shared__ short sB[MB * LDB];
    __shared__ int sSrc[MB], sDst[MB];

    const int tid = threadIdx.x;
    const int e0  = blockIdx.x * MB;
    const float e2 = 1.f + eps2p[0];
    {
        int row  = tid >> 2;
        int cseg = (tid & 3) << 5;
        int e = e0 + row;
        int sIdx = 0, dIdx = 0;
        bool ev = (e < E);
        if (ev) { sIdx = eidx[e]; dIdx = eidx[E + e]; }
        if ((tid & 3) == 0) { sSrc[row] = sIdx; sDst[row] = dIdx; }
        short* rowA = sA + row * LDA;
        if (ev) {
            const float4* sp = (const float4*)(node_rep + (size_t)sIdx * H + cseg);
            const float4* dp = (const float4*)(node_rep + (size_t)dIdx * H + cseg);
            const float4* ep = (const float4*)(edge_rep + (size_t)e * H + cseg);
            #pragma unroll
            for (int j = 0; j < 8; ++j) {
                float4 a = sp[j], b = dp[j], c = ep[j];
                int cc = cseg + 4 * j;
                s16x4 lift = { f2bf(a.x + b.x), f2bf(a.y + b.y),
                               f2bf(a.z + b.z), f2bf(a.w + b.w) };
                s16x4 er   = { f2bf(c.x), f2bf(c.y), f2bf(c.z), f2bf(c.w) };
                *(s16x4*)&rowA[cc]      = lift;
                *(s16x4*)&rowA[H + cc]  = er;
            }
        } else {
            s16x4 z = {0, 0, 0, 0};
            #pragma unroll
            for (int j = 0; j < 8; ++j) {
                int cc = cseg + 4 * j;
                *(s16x4*)&rowA[cc]     = z;
                *(s16x4*)&rowA[H + cc] = z;
            }
        }
    }
    __syncthreads();

    const int wave = tid >> 6;
    const int lane = tid & 63;
    const int m = lane & 15;
    const int q = lane >> 4;

    f32x4 zero = {0.f, 0.f, 0.f, 0.f};
    f32x4 acc[4][2];
    #pragma unroll
    for (int mt = 0; mt < 4; ++mt)
        #pragma unroll
        for (int nt = 0; nt < 2; ++nt) acc[mt][nt] = zero;

    #pragma unroll
    for (int ks = 0; ks < 8; ++ks) {
        int k0 = ks * 32 + q * 8;
        bf16x8 aF[4];
        #pragma unroll
        for (int mt = 0; mt < 4; ++mt)
            aF[mt] = *(const bf16x8*)&sA[(mt * 16 + m) * LDA + k0];
        bf16x8 bF[2];
        #pragma unroll
        for (int nt = 0; nt < 2; ++nt) {
            int n = (wave << 5) + (nt << 4) + m;
            bF[nt] = *(const bf16x8*)&W1T[n * 256 + k0];
        }
        #pragma unroll
        for (int mt = 0; mt < 4; ++mt)
            #pragma unroll
            for (int nt = 0; nt < 2; ++nt)
                acc[mt][nt] = __builtin_amdgcn_mfma_f32_16x16x32_bf16(
                    aF[mt], bF[nt], acc[mt][nt], 0, 0, 0);
    }

    #pragma unroll
    for (int mt = 0; mt < 4; ++mt) {
        #pragma unroll
        for (int nt = 0; nt < 2; ++nt) {
            int col = (wave << 5) + (nt << 4) + m;
            #pragma unroll
            for (int i = 0; i < 4; ++i) {
                int rr = (mt << 4) + (q << 2) + i;
                if (e0 + rr < E) {
                    float h = acc[mt][nt][i];
                    h = h > 0.f ? h : 0.f;
                    int sn = sSrc[rr], dn = sDst[rr];
                    atomicAdd(lvl + (size_t)sn * H + col, h);
                    atomicAdd(lvl + (size_t)dn * H + col, h);
                    float b2 = e2 * h + bf2f(sA[rr * LDA + col]);
                    sB[rr * LDB + col] = f2bf(b2);
                }
            }
        }
    }
    __syncthreads();

    f32x4 acc2[4][2];
    #pragma unroll
    for (int mt = 0; mt < 4; ++mt)
        #pragma unroll
        for (int nt = 0; nt < 2; ++nt) acc2[mt][nt] = zero;

    #pragma unroll
    for (int ks = 0; ks < 4; ++ks) {
        int k0 = ks * 32 + q * 8;
        bf16x8 aF[4];
        #pragma unroll
        for (int mt = 0; mt < 4; ++mt)
            aF[mt] = *(const bf16x8*)&sB[(mt * 16 + m) * LDB + k0];
        bf16x8 bF[2];
        #pragma unroll
        for (int nt = 0; nt < 2; ++nt) {
            int n = (wave << 5) + (nt << 4) + m;
            bF[nt] = *(const bf16x8*)&WLT[n * 128 + k0];
        }
        #pragma unroll
        for (int mt = 0; mt < 4; ++mt)
            #pragma unroll
            for (int nt = 0; nt < 2; ++nt)
                acc2[mt][nt] = __builtin_amdgcn_mfma_f32_16x16x32_bf16(
                    aF[mt], bF[nt], acc2[mt][nt], 0, 0, 0);
    }

    #pragma unroll
    for (int mt = 0; mt < 4; ++mt) {
        #pragma unroll
        for (int nt = 0; nt < 2; ++nt) {
            int col = (wave << 5) + (nt << 4) + m;
            #pragma unroll
            for (int i = 0; i < 4; ++i) {
                int rr = (mt << 4) + (q << 2) + i;
                if (e0 + rr < E) {
                    float v = acc2[mt][nt][i];
                    edge_out[(size_t)(e0 + rr) * H + col] = v > 0.f ? v : 0.f;
                }
            }
        }
    }
}

// ---------------- node kernel ----------------
// node_out = relu(((1+eps1)*node_rep + lvl) @ W2); lvl may alias node_out.
__global__ __launch_bounds__(256) void node_kernel(
    const float* __restrict__ node_rep, const float* __restrict__ lvl,
    const short* __restrict__ W2T, const float* __restrict__ eps1p,
    float* __restrict__ node_out, int N)
{
    __shared__ short sA[MB * LDB];

    const int tid = threadIdx.x;
    const int r0  = blockIdx.x * MB;
    const float e1 = 1.f + eps1p[0];

    {
        int row  = tid >> 2;
        int cseg = (tid & 3) << 5;
        int r = r0 + row;
        short* rowA = sA + row * LDB;
        if (r < N) {
            const float4* np = (const float4*)(node_rep + (size_t)r * H + cseg);
            const float4* lp = (const float4*)(lvl + (size_t)r * H + cseg);
            #pragma unroll
            for (int j = 0; j < 8; ++j) {
                float4 a = np[j], b = lp[j];
                int cc = cseg + 4 * j;
                s16x4 v = { f2bf(e1 * a.x + b.x), f2bf(e1 * a.y + b.y),
                            f2bf(e1 * a.z + b.z), f2bf(e1 * a.w + b.w) };
                *(s16x4*)&rowA[cc] = v;
            }
        } else {
            s16x4 z = {0, 0, 0, 0};
            #pragma unroll
            for (int j = 0; j < 8; ++j) *(s16x4*)&rowA[cseg + 4 * j] = z;
        }
    }
    __syncthreads();

    const int wave = tid >> 6;
    const int lane = tid & 63;
    const int m = lane & 15;
    const int q = lane >> 4;

    f32x4 zero = {0.f, 0.f, 0.f, 0.f};
    f32x4 acc[4][2];
    #pragma unroll
    for (int mt = 0; mt < 4; ++mt)
        #pragma unroll
        for (int nt = 0; nt < 2; ++nt) acc[mt][nt] = zero;

    #pragma unroll
    for (int ks = 0; ks < 4; ++ks) {
        int k0 = ks * 32 + q * 8;
        bf16x8 aF[4];
        #pragma unroll
        for (int mt = 0; mt < 4; ++mt)
            aF[mt] = *(const bf16x8*)&sA[(mt * 16 + m) * LDB + k0];
        bf16x8 bF[2];
        #pragma unroll
        for (int nt = 0; nt < 2; ++nt) {
            int n = (wave << 5) + (nt << 4) + m;
            bF[nt] = *(const bf16x8*)&W2T[n * 128 + k0];
        }
        #pragma unroll
        for (int mt = 0; mt < 4; ++mt)
            #pragma unroll
            for (int nt = 0; nt < 2; ++nt)
                acc[mt][nt] = __builtin_amdgcn_mfma_f32_16x16x32_bf16(
                    aF[mt], bF[nt], acc[mt][nt], 0, 0, 0);
    }

    #pragma unroll
    for (int mt = 0; mt < 4; ++mt) {
        #pragma unroll
        for (int nt = 0; nt < 2; ++nt) {
            int col = (wave << 5) + (nt << 4) + m;
            #pragma unroll
            for (int i = 0; i < 4; ++i) {
                int rr = (mt << 4) + (q << 2) + i;
                if (r0 + rr < N) {
                    float v = acc[mt][nt][i];
                    node_out[(size_t)(r0 + rr) * H + col] = v > 0.f ? v : 0.f;
                }
            }
        }
    }
}

static inline size_t algn(size_t x) { return (x + 255) & ~(size_t)255; }

extern "C" void kernel_launch(void* const* d_in, const int* in_sizes, int n_in,
                              void* d_out, int out_size, void* d_ws, size_t ws_size,
                              hipStream_t stream) {
    const float* node_rep = (const float*)d_in[0];
    const float* edge_rep = (const float*)d_in[1];
    const int*   eidx     = (const int*)d_in[2];
    const float* W1       = (const float*)d_in[3];
    const float* W2       = (const float*)d_in[4];
    const float* WL       = (const float*)d_in[5];
    const float* eps1     = (const float*)d_in[6];
    const float* eps2     = (const float*)d_in[7];

    const int N = in_sizes[0] / H;     // 50000
    const int E = in_sizes[1] / H;     // 800000

    float* node_out = (float*)d_out;
    float* edge_out = (float*)d_out + (size_t)N * H;
    float* lvl = node_out;             // lvl aliases node_out (node_kernel is in-place safe)

    char* ws = (char*)d_ws;
    short* W1T = (short*)ws;                       // 64 KB
    short* W2T = (short*)(ws + 65536);             // 32 KB
    short* WLT = (short*)(ws + 65536 + 32768);     // 32 KB
    size_t off = 131072;

    int* deg       = (int*)(ws + off); off += algn((size_t)N * 4);
    int* row_start = (int*)(ws + off); off += algn((size_t)(N + 1) * 4);
    int* cursor    = (int*)(ws + off); off += algn((size_t)N * 4);
    int* csr       = (int*)(ws + off); off += algn((size_t)2 * E * 4);
    const size_t need_small = off;
    short* hbuf    = (short*)(ws + off); off += algn((size_t)E * H * sizeof(short));
    const size_t need_big = off;
    short* nodeB   = (short*)(ws + off); off += algn((size_t)N * H * sizeof(short));
    const size_t need_nb = off;

    prep_weights<<<128, 256, 0, stream>>>(W1, W2, WL, W1T, W2T, WLT);

    const int twoE = 2 * E;
    const int egrid = (E + MB - 1) / MB;
    const int ngrid = (N + MB - 1) / MB;

    if (ws_size >= need_small) {
        // build CSR incidence lists (int atomics only: 2E ops)
        hipMemsetAsync(deg, 0, (size_t)N * 4, stream);
        count_deg<<<(twoE + 255) / 256, 256, 0, stream>>>(eidx, deg, twoE);
        scan_deg<<<1, 1024, 0, stream>>>(deg, row_start, cursor, N);
        fill_csr<<<(twoE + 255) / 256, 256, 0, stream>>>(eidx, cursor, csr, E);

        if (ws_size >= need_big) {
            if (ws_size >= need_nb) {
                int total8 = (N * H) / 8;
                prep_nodes<<<(total8 + 255) / 256, 256, 0, stream>>>(
                    node_rep, nodeB, total8);
                int nTiles = (E + MB - 1) / MB;
                int pgrid = (nTiles + TPB - 1) / TPB;
                edge_pipe<<<pgrid, 256, 0, stream>>>(
                    nodeB, edge_rep, eidx, W1T, WLT, eps2,
                    hbuf, edge_out, E, nTiles);
            } else {
                edge_fused_nb<<<egrid, 256, 0, stream>>>(
                    node_rep, edge_rep, eidx, W1T, WLT, eps2, hbuf, edge_out, E);
            }
            node_aggr_bf16<<<(N + 3) / 4, 256, 0, stream>>>(
                (const uint2*)hbuf, csr, row_start, lvl, N);
            node_kernel<<<ngrid, 256, 0, stream>>>(
                node_rep, lvl, W2T, eps1, node_out, N);
        } else {
            // PATH B: h f32 transits through edge_out region
            edge_h_kernel<<<egrid, 256, 0, stream>>>(
                node_rep, edge_rep, eidx, W1T, edge_out, E);
            node_aggr_f32<<<(N + 3) / 4, 256, 0, stream>>>(
                edge_out, csr, row_start, lvl, N);
            node_kernel<<<ngrid, 256, 0, stream>>>(
                node_rep, lvl, W2T, eps1, node_out, N);
            edge_finalize<<<egrid, 256, 0, stream>>>(
                node_rep, eidx, WLT, eps2, edge_out, E);
        }
    } else {
        // LEGACY: atomic scatter
        hipMemsetAsync(lvl, 0, (size_t)N * H * sizeof(float), stream);
        edge_kernel<<<egrid, 256, 0, stream>>>(
            node_rep, edge_rep, eidx, W1T, WLT, eps2, lvl, edge_out, E);
        node_kernel<<<ngrid, 256, 0, stream>>>(
            node_rep, lvl, W2T, eps1, node_out, N);
    }
}

// Round 5
// 1331.623 us; speedup vs baseline: 1.2556x; 1.1564x over previous
//
#include <hip/hip_runtime.h>

#define H 128
#define MB 64          // edges (or nodes) per block
#define TPB 4          // tiles per block in edge_pipe
#define LDA 264        // LDS row stride (elems) for the [64 x 256] concat tile (+8 pad)
#define LDB 136        // LDS row stride for [64 x 128] tiles (+8 pad)

typedef __attribute__((ext_vector_type(8))) short bf16x8;
typedef __attribute__((ext_vector_type(4))) short s16x4;
typedef __attribute__((ext_vector_type(4))) float f32x4;

__device__ __forceinline__ short f2bf(float f) {
    union { float f; unsigned u; } v; v.f = f;
    unsigned r = v.u + 0x7FFF + ((v.u >> 16) & 1);   // RTNE
    return (short)(r >> 16);
}
__device__ __forceinline__ float bf2f(short s) {
    union { unsigned u; float f; } v;
    v.u = ((unsigned)(unsigned short)s) << 16;
    return v.f;
}
__device__ __forceinline__ float bflo(unsigned u) {
    union { unsigned u; float f; } v; v.u = u << 16; return v.f;
}
__device__ __forceinline__ float bfhi(unsigned u) {
    union { unsigned u; float f; } v; v.u = u & 0xffff0000u; return v.f;
}

// ---------------- weight prep: fp32 [K,N] -> bf16 transposed [N,K] ----------------
__global__ __launch_bounds__(256) void prep_weights(
    const float* __restrict__ W1, const float* __restrict__ W2,
    const float* __restrict__ WL,
    short* __restrict__ W1T, short* __restrict__ W2T, short* __restrict__ WLT)
{
    int tid = blockIdx.x * 256 + threadIdx.x;      // 0..32767
    {   // W1: [256,128] -> W1T [128][256]
        int n = tid >> 8, k = tid & 255;
        W1T[n * 256 + k] = f2bf(W1[k * 128 + n]);
    }
    if (tid < 16384) {  // W2, W_lift: [128,128] -> [128][128]
        int n = tid >> 7, k = tid & 127;
        W2T[n * 128 + k] = f2bf(W2[k * 128 + n]);
        WLT[n * 128 + k] = f2bf(WL[k * 128 + n]);
    }
}

// node_rep fp32 -> bf16 copy (halves the gather bytes in the edge kernel)
__global__ __launch_bounds__(256) void prep_nodes(
    const float* __restrict__ nr, short* __restrict__ nodeB, int total8)
{
    int t = blockIdx.x * 256 + threadIdx.x;
    if (t >= total8) return;
    const float4* p = (const float4*)nr + (size_t)t * 2;
    float4 a = p[0], b = p[1];
    bf16x8 v = { f2bf(a.x), f2bf(a.y), f2bf(a.z), f2bf(a.w),
                 f2bf(b.x), f2bf(b.y), f2bf(b.z), f2bf(b.w) };
    *(bf16x8*)(nodeB + (size_t)t * 8) = v;
}

// ---------------- CSR build ----------------
__global__ __launch_bounds__(256) void count_deg(
    const int* __restrict__ eidx, int* __restrict__ deg, int twoE)
{
    int t = blockIdx.x * 256 + threadIdx.x;
    if (t < twoE) atomicAdd(&deg[eidx[t]], 1);
}

// single-block exclusive scan of deg[N] -> row_start[N+1] and cursor[N]
__global__ __launch_bounds__(1024) void scan_deg(
    const int* __restrict__ deg, int* __restrict__ row_start,
    int* __restrict__ cursor, int N)
{
    __shared__ int part[1024];
    const int t = threadIdx.x;
    const int chunk = (N + 1023) >> 10;
    const int b = t * chunk;
    const int e = (b + chunk < N) ? (b + chunk) : N;
    int s = 0;
    for (int j = b; j < e; ++j) s += deg[j];
    part[t] = s;
    __syncthreads();
    for (int off = 1; off < 1024; off <<= 1) {
        int v = part[t];
        int u = (t >= off) ? part[t - off] : 0;
        __syncthreads();
        part[t] = v + u;
        __syncthreads();
    }
    int run = (t == 0) ? 0 : part[t - 1];
    for (int j = b; j < e; ++j) {
        int d = deg[j];
        row_start[j] = run;
        cursor[j]    = run;
        run += d;
    }
    if (t == 1023) row_start[N] = part[1023];
}

__global__ __launch_bounds__(256) void fill_csr(
    const int* __restrict__ eidx, int* __restrict__ cursor,
    int* __restrict__ csr, int E)
{
    int t = blockIdx.x * 256 + threadIdx.x;
    if (t < 2 * E) {
        int node = eidx[t];
        int e = (t < E) ? t : (t - E);
        int pos = atomicAdd(&cursor[node], 1);
        csr[pos] = e;
    }
}

// ---------------- PATH A: pipelined fused edge kernel (v2) ----------------
// Per block: TPB tiles of 64 edges. Next tile's random nodeB gathers prefetch
// into registers under GEMM1 (NO occupancy cap -> no spills). lift@WL is folded
// into acc2 during GEMM1; epilogue writes only h (bf16) into the dead
// edge_rep half of sA; hbuf dump is a coalesced 16B/lane LDS->global copy;
// GEMM2 computes h@WL and edge_out = relu(acc2 + e2*(h@WL)).
__global__ __launch_bounds__(256) void edge_pipe(
    const short* __restrict__ nodeB, const float* __restrict__ edge_rep,
    const int* __restrict__ eidx,
    const short* __restrict__ W1T, const short* __restrict__ WLT,
    const float* __restrict__ eps2p,
    short* __restrict__ hbuf, float* __restrict__ edge_out,
    int E, int nTiles)
{
    __shared__ short sA[MB * LDA];   // cols [0,128)=lift, [128,256)=edge_rep then h

    const int tid  = threadIdx.x;
    const int row  = tid >> 2;          // 0..63
    const int cseg = (tid & 3) << 5;    // 0,32,64,96
    const int wave = tid >> 6;
    const int lane = tid & 63;
    const int m = lane & 15;            // A row / B col / D col
    const int q = lane >> 4;            // k-quad / D row group
    const float e2 = 1.f + eps2p[0];

    int t = blockIdx.x * TPB;
    if (t >= nTiles) return;
    const int tEnd = (t + TPB < nTiles) ? (t + TPB) : nTiles;

    // ---- prologue: gather tile t's node rows into registers ----
    bf16x8 pS[4], pD[4];
    bool pv;
    {
        int e = t * MB + row;
        pv = (e < E);
        if (pv) {
            int sIdx = eidx[e], dIdx = eidx[E + e];
            const bf16x8* sp = (const bf16x8*)(nodeB + (size_t)sIdx * H + cseg);
            const bf16x8* dp = (const bf16x8*)(nodeB + (size_t)dIdx * H + cseg);
            #pragma unroll
            for (int j = 0; j < 4; ++j) { pS[j] = sp[j]; pD[j] = dp[j]; }
        }
    }

    for (; t < tEnd; ++t) {
        const int e0 = t * MB;

        // ---- stage: lift from prefetched regs; edge_rep streamed ----
        {
            short* rowA = sA + row * LDA;
            if (pv) {
                const float4* ep = (const float4*)(edge_rep + (size_t)(e0 + row) * H + cseg);
                float4 ev[8];
                #pragma unroll
                for (int j = 0; j < 8; ++j) ev[j] = ep[j];
                #pragma unroll
                for (int j = 0; j < 4; ++j) {
                    bf16x8 lift;
                    #pragma unroll
                    for (int k = 0; k < 8; ++k)
                        lift[k] = f2bf(bf2f(pS[j][k]) + bf2f(pD[j][k]));
                    *(bf16x8*)&rowA[cseg + 8 * j] = lift;
                }
                #pragma unroll
                for (int j = 0; j < 8; ++j) {
                    float4 c = ev[j];
                    s16x4 er = { f2bf(c.x), f2bf(c.y), f2bf(c.z), f2bf(c.w) };
                    *(s16x4*)&rowA[H + cseg + 4 * j] = er;
                }
            } else {
                s16x4 z = {0, 0, 0, 0};
                #pragma unroll
                for (int j = 0; j < 8; ++j) {
                    int cc = cseg + 4 * j;
                    *(s16x4*)&rowA[cc]     = z;
                    *(s16x4*)&rowA[H + cc] = z;
                }
            }
        }
        __syncthreads();

        // ---- issue next tile's gathers (latency hidden under GEMM1) ----
        if (t + 1 < tEnd) {
            int e = (t + 1) * MB + row;
            pv = (e < E);
            if (pv) {
                int sIdx = eidx[e], dIdx = eidx[E + e];
                const bf16x8* sp = (const bf16x8*)(nodeB + (size_t)sIdx * H + cseg);
                const bf16x8* dp = (const bf16x8*)(nodeB + (size_t)dIdx * H + cseg);
                #pragma unroll
                for (int j = 0; j < 4; ++j) { pS[j] = sp[j]; pD[j] = dp[j]; }
            }
        }

        // ---- GEMM1: acc = concat @ W1T;  acc2 = lift @ WLT (ks<4 fold) ----
        f32x4 zero = {0.f, 0.f, 0.f, 0.f};
        f32x4 acc[4][2], acc2[4][2];
        #pragma unroll
        for (int mt = 0; mt < 4; ++mt)
            #pragma unroll
            for (int nt = 0; nt < 2; ++nt) { acc[mt][nt] = zero; acc2[mt][nt] = zero; }

        #pragma unroll
        for (int ks = 0; ks < 8; ++ks) {
            int k0 = ks * 32 + q * 8;
            bf16x8 aF[4];
            #pragma unroll
            for (int mt = 0; mt < 4; ++mt)
                aF[mt] = *(const bf16x8*)&sA[(mt * 16 + m) * LDA + k0];
            bf16x8 bF[2];
            #pragma unroll
            for (int nt = 0; nt < 2; ++nt) {
                int n = (wave << 5) + (nt << 4) + m;
                bF[nt] = *(const bf16x8*)&W1T[n * 256 + k0];
            }
            #pragma unroll
            for (int mt = 0; mt < 4; ++mt)
                #pragma unroll
                for (int nt = 0; nt < 2; ++nt)
                    acc[mt][nt] = __builtin_amdgcn_mfma_f32_16x16x32_bf16(
                        aF[mt], bF[nt], acc[mt][nt], 0, 0, 0);
            if (ks < 4) {
                bf16x8 bL[2];
                #pragma unroll
                for (int nt = 0; nt < 2; ++nt) {
                    int n = (wave << 5) + (nt << 4) + m;
                    bL[nt] = *(const bf16x8*)&WLT[n * 128 + k0];
                }
                #pragma unroll
                for (int mt = 0; mt < 4; ++mt)
                    #pragma unroll
                    for (int nt = 0; nt < 2; ++nt)
                        acc2[mt][nt] = __builtin_amdgcn_mfma_f32_16x16x32_bf16(
                            aF[mt], bL[nt], acc2[mt][nt], 0, 0, 0);
            }
        }
        __syncthreads();   // all waves done reading sA

        // ---- epilogue: h = relu(acc) -> bf16 into the dead edge_rep half ----
        #pragma unroll
        for (int mt = 0; mt < 4; ++mt) {
            #pragma unroll
            for (int nt = 0; nt < 2; ++nt) {
                int col = (wave << 5) + (nt << 4) + m;
                #pragma unroll
                for (int i = 0; i < 4; ++i) {
                    int rr = (mt << 4) + (q << 2) + i;
                    float h = acc[mt][nt][i];
                    h = h > 0.f ? h : 0.f;
                    sA[rr * LDA + H + col] = f2bf(h);
                }
            }
        }
        __syncthreads();

        // ---- coalesced hbuf dump (16B/lane from LDS) ----
        if (e0 + row < E) {
            #pragma unroll
            for (int j = 0; j < 4; ++j) {
                bf16x8 hv = *(const bf16x8*)&sA[row * LDA + H + cseg + 8 * j];
                *(bf16x8*)&hbuf[(size_t)(e0 + row) * H + cseg + 8 * j] = hv;
            }
        }

        // ---- GEMM2: acc3 = h @ WLT; edge_out = relu(acc2 + e2*acc3) ----
        f32x4 acc3[4][2];
        #pragma unroll
        for (int mt = 0; mt < 4; ++mt)
            #pragma unroll
            for (int nt = 0; nt < 2; ++nt) acc3[mt][nt] = zero;

        #pragma unroll
        for (int ks = 0; ks < 4; ++ks) {
            int k0 = ks * 32 + q * 8;
            bf16x8 aF[4];
            #pragma unroll
            for (int mt = 0; mt < 4; ++mt)
                aF[mt] = *(const bf16x8*)&sA[(mt * 16 + m) * LDA + H + k0];
            bf16x8 bF[2];
            #pragma unroll
            for (int nt = 0; nt < 2; ++nt) {
                int n = (wave << 5) + (nt << 4) + m;
                bF[nt] = *(const bf16x8*)&WLT[n * 128 + k0];
            }
            #pragma unroll
            for (int mt = 0; mt < 4; ++mt)
                #pragma unroll
                for (int nt = 0; nt < 2; ++nt)
                    acc3[mt][nt] = __builtin_amdgcn_mfma_f32_16x16x32_bf16(
                        aF[mt], bF[nt], acc3[mt][nt], 0, 0, 0);
        }

        #pragma unroll
        for (int mt = 0; mt < 4; ++mt) {
            #pragma unroll
            for (int nt = 0; nt < 2; ++nt) {
                int col = (wave << 5) + (nt << 4) + m;
                #pragma unroll
                for (int i = 0; i < 4; ++i) {
                    int rr = (mt << 4) + (q << 2) + i;
                    if (e0 + rr < E) {
                        float v = acc2[mt][nt][i] + e2 * acc3[mt][nt][i];
                        edge_out[(size_t)(e0 + rr) * H + col] = v > 0.f ? v : 0.f;
                    }
                }
            }
        }
        __syncthreads();   // GEMM2 + dump reads done before next stage overwrites sA
    }
}

// ---------------- node aggregation v2: quarter-wave per edge ----------------
// one wave per node; 4 edges in flight per iter, unroll 2 -> 8 outstanding
// 16B gathers; cross-quarter shfl reduce; coalesced 32B/lane store.
__global__ __launch_bounds__(256) void node_aggr4(
    const uint4* __restrict__ hb, const int* __restrict__ csr,
    const int* __restrict__ row_start, float* __restrict__ lvl, int N)
{
    const int wid = threadIdx.x >> 6, lane = threadIdx.x & 63;
    const int n = blockIdx.x * 4 + wid;
    if (n >= N) return;
    const int qt = lane >> 4, li = lane & 15;    // lane covers cols li*8..li*8+7
    const int beg = row_start[n], end = row_start[n + 1];
    float a0 = 0.f, a1 = 0.f, a2 = 0.f, a3 = 0.f;
    float a4 = 0.f, a5 = 0.f, a6 = 0.f, a7 = 0.f;

    int i = beg;
    for (; i + 8 <= end; i += 8) {
        int eA = csr[i + qt], eB = csr[i + 4 + qt];
        uint4 vA = hb[(size_t)eA * 16 + li];
        uint4 vB = hb[(size_t)eB * 16 + li];
        a0 += bflo(vA.x) + bflo(vB.x);  a1 += bfhi(vA.x) + bfhi(vB.x);
        a2 += bflo(vA.y) + bflo(vB.y);  a3 += bfhi(vA.y) + bfhi(vB.y);
        a4 += bflo(vA.z) + bflo(vB.z);  a5 += bfhi(vA.z) + bfhi(vB.z);
        a6 += bflo(vA.w) + bflo(vB.w);  a7 += bfhi(vA.w) + bfhi(vB.w);
    }
    if (i + 4 <= end) {
        int eA = csr[i + qt];
        uint4 vA = hb[(size_t)eA * 16 + li];
        a0 += bflo(vA.x);  a1 += bfhi(vA.x);
        a2 += bflo(vA.y);  a3 += bfhi(vA.y);
        a4 += bflo(vA.z);  a5 += bfhi(vA.z);
        a6 += bflo(vA.w);  a7 += bfhi(vA.w);
        i += 4;
    }
    int rem = end - i;     // 0..3
    if (qt < rem) {
        int eA = csr[i + qt];
        uint4 vA = hb[(size_t)eA * 16 + li];
        a0 += bflo(vA.x);  a1 += bfhi(vA.x);
        a2 += bflo(vA.y);  a3 += bfhi(vA.y);
        a4 += bflo(vA.z);  a5 += bfhi(vA.z);
        a6 += bflo(vA.w);  a7 += bfhi(vA.w);
    }
    // reduce across the 4 quarters (lanes with same li)
    a0 += __shfl_xor(a0, 16); a1 += __shfl_xor(a1, 16);
    a2 += __shfl_xor(a2, 16); a3 += __shfl_xor(a3, 16);
    a4 += __shfl_xor(a4, 16); a5 += __shfl_xor(a5, 16);
    a6 += __shfl_xor(a6, 16); a7 += __shfl_xor(a7, 16);
    a0 += __shfl_xor(a0, 32); a1 += __shfl_xor(a1, 32);
    a2 += __shfl_xor(a2, 32); a3 += __shfl_xor(a3, 32);
    a4 += __shfl_xor(a4, 32); a5 += __shfl_xor(a5, 32);
    a6 += __shfl_xor(a6, 32); a7 += __shfl_xor(a7, 32);
    if (qt == 0) {
        float* dst = lvl + (size_t)n * H + li * 8;
        float4 o0; o0.x = a0; o0.y = a1; o0.z = a2; o0.w = a3;
        float4 o1; o1.x = a4; o1.y = a5; o1.z = a6; o1.w = a7;
        *(float4*)dst = o0;
        *(float4*)(dst + 4) = o1;
    }
}

// ---------------- LEGACY edge kernel (atomic scatter) -- tiny-ws fallback ----
__global__ __launch_bounds__(256) void edge_kernel(
    const float* __restrict__ node_rep, const float* __restrict__ edge_rep,
    const int* __restrict__ eidx,
    const short* __restrict__ W1T, const short* __restrict__ WLT,
    const float* __restrict__ eps2p,
    float* __restrict__ lvl, float* __restrict__ edge_out, int E)
{
    __shared__ short sA[MB * LDA];
    __shared__ short sB[MB * LDB];
    __shared__ int sSrc[MB], sDst[MB];

    const int tid = threadIdx.x;
    const int e0  = blockIdx.x * MB;
    const float e2 = 1.f + eps2p[0];
    {
        int row  = tid >> 2;
        int cseg = (tid & 3) << 5;
        int e = e0 + row;
        int sIdx = 0, dIdx = 0;
        bool ev = (e < E);
        if (ev) { sIdx = eidx[e]; dIdx = eidx[E + e]; }
        if ((tid & 3) == 0) { sSrc[row] = sIdx; sDst[row] = dIdx; }
        short* rowA = sA + row * LDA;
        if (ev) {
            const float4* sp = (const float4*)(node_rep + (size_t)sIdx * H + cseg);
            const float4* dp = (const float4*)(node_rep + (size_t)dIdx * H + cseg);
            const float4* ep = (const float4*)(edge_rep + (size_t)e * H + cseg);
            #pragma unroll
            for (int j = 0; j < 8; ++j) {
                float4 a = sp[j], b = dp[j], c = ep[j];
                int cc = cseg + 4 * j;
                s16x4 lift = { f2bf(a.x + b.x), f2bf(a.y + b.y),
                               f2bf(a.z + b.z), f2bf(a.w + b.w) };
                s16x4 er   = { f2bf(c.x), f2bf(c.y), f2bf(c.z), f2bf(c.w) };
                *(s16x4*)&rowA[cc]      = lift;
                *(s16x4*)&rowA[H + cc]  = er;
            }
        } else {
            s16x4 z = {0, 0, 0, 0};
            #pragma unroll
            for (int j = 0; j < 8; ++j) {
                int cc = cseg + 4 * j;
                *(s16x4*)&rowA[cc]     = z;
                *(s16x4*)&rowA[H + cc] = z;
            }
        }
    }
    __syncthreads();

    const int wave = tid >> 6;
    const int lane = tid & 63;
    const int m = lane & 15;
    const int q = lane >> 4;

    f32x4 zero = {0.f, 0.f, 0.f, 0.f};
    f32x4 acc[4][2];
    #pragma unroll
    for (int mt = 0; mt < 4; ++mt)
        #pragma unroll
        for (int nt = 0; nt < 2; ++nt) acc[mt][nt] = zero;

    #pragma unroll
    for (int ks = 0; ks < 8; ++ks) {
        int k0 = ks * 32 + q * 8;
        bf16x8 aF[4];
        #pragma unroll
        for (int mt = 0; mt < 4; ++mt)
            aF[mt] = *(const bf16x8*)&sA[(mt * 16 + m) * LDA + k0];
        bf16x8 bF[2];
        #pragma unroll
        for (int nt = 0; nt < 2; ++nt) {
            int n = (wave << 5) + (nt << 4) + m;
            bF[nt] = *(const bf16x8*)&W1T[n * 256 + k0];
        }
        #pragma unroll
        for (int mt = 0; mt < 4; ++mt)
            #pragma unroll
            for (int nt = 0; nt < 2; ++nt)
                acc[mt][nt] = __builtin_amdgcn_mfma_f32_16x16x32_bf16(
                    aF[mt], bF[nt], acc[mt][nt], 0, 0, 0);
    }

    #pragma unroll
    for (int mt = 0; mt < 4; ++mt) {
        #pragma unroll
        for (int nt = 0; nt < 2; ++nt) {
            int col = (wave << 5) + (nt << 4) + m;
            #pragma unroll
            for (int i = 0; i < 4; ++i) {
                int rr = (mt << 4) + (q << 2) + i;
                if (e0 + rr < E) {
                    float h = acc[mt][nt][i];
                    h = h > 0.f ? h : 0.f;
                    int sn = sSrc[rr], dn = sDst[rr];
                    atomicAdd(lvl + (size_t)sn * H + col, h);
                    atomicAdd(lvl + (size_t)dn * H + col, h);
                    float b2 = e2 * h + bf2f(sA[rr * LDA + col]);
                    sB[rr * LDB + col] = f2bf(b2);
                }
            }
        }
    }
    __syncthreads();

    f32x4 acc2[4][2];
    #pragma unroll
    for (int mt = 0; mt < 4; ++mt)
        #pragma unroll
        for (int nt = 0; nt < 2; ++nt) acc2[mt][nt] = zero;

    #pragma unroll
    for (int ks = 0; ks < 4; ++ks) {
        int k0 = ks * 32 + q * 8;
        bf16x8 aF[4];
        #pragma unroll
        for (int mt = 0; mt < 4; ++mt)
            aF[mt] = *(const bf16x8*)&sB[(mt * 16 + m) * LDB + k0];
        bf16x8 bF[2];
        #pragma unroll
        for (int nt = 0; nt < 2; ++nt) {
            int n = (wave << 5) + (nt << 4) + m;
            bF[nt] = *(const bf16x8*)&WLT[n * 128 + k0];
        }
        #pragma unroll
        for (int mt = 0; mt < 4; ++mt)
            #pragma unroll
            for (int nt = 0; nt < 2; ++nt)
                acc2[mt][nt] = __builtin_amdgcn_mfma_f32_16x16x32_bf16(
                    aF[mt], bF[nt], acc2[mt][nt], 0, 0, 0);
    }

    #pragma unroll
    for (int mt = 0; mt < 4; ++mt) {
        #pragma unroll
        for (int nt = 0; nt < 2; ++nt) {
            int col = (wave << 5) + (nt << 4) + m;
            #pragma unroll
            for (int i = 0; i < 4; ++i) {
                int rr = (mt << 4) + (q << 2) + i;
                if (e0 + rr < E) {
                    float v = acc2[mt][nt][i];
                    edge_out[(size_t)(e0 + rr) * H + col] = v > 0.f ? v : 0.f;
                }
            }
        }
    }
}

// ---------------- node kernel ----------------
// node_out = relu(((1+eps1)*node_rep + lvl) @ W2); lvl may alias node_out.
__global__ __launch_bounds__(256) void node_kernel(
    const float* __restrict__ node_rep, const float* __restrict__ lvl,
    const short* __restrict__ W2T, const float* __restrict__ eps1p,
    float* __restrict__ node_out, int N)
{
    __shared__ short sA[MB * LDB];

    const int tid = threadIdx.x;
    const int r0  = blockIdx.x * MB;
    const float e1 = 1.f + eps1p[0];

    {
        int row  = tid >> 2;
        int cseg = (tid & 3) << 5;
        int r = r0 + row;
        short* rowA = sA + row * LDB;
        if (r < N) {
            const float4* np = (const float4*)(node_rep + (size_t)r * H + cseg);
            const float4* lp = (const float4*)(lvl + (size_t)r * H + cseg);
            #pragma unroll
            for (int j = 0; j < 8; ++j) {
                float4 a = np[j], b = lp[j];
                int cc = cseg + 4 * j;
                s16x4 v = { f2bf(e1 * a.x + b.x), f2bf(e1 * a.y + b.y),
                            f2bf(e1 * a.z + b.z), f2bf(e1 * a.w + b.w) };
                *(s16x4*)&rowA[cc] = v;
            }
        } else {
            s16x4 z = {0, 0, 0, 0};
            #pragma unroll
            for (int j = 0; j < 8; ++j) *(s16x4*)&rowA[cseg + 4 * j] = z;
        }
    }
    __syncthreads();

    const int wave = tid >> 6;
    const int lane = tid & 63;
    const int m = lane & 15;
    const int q = lane >> 4;

    f32x4 zero = {0.f, 0.f, 0.f, 0.f};
    f32x4 acc[4][2];
    #pragma unroll
    for (int mt = 0; mt < 4; ++mt)
        #pragma unroll
        for (int nt = 0; nt < 2; ++nt) acc[mt][nt] = zero;

    #pragma unroll
    for (int ks = 0; ks < 4; ++ks) {
        int k0 = ks * 32 + q * 8;
        bf16x8 aF[4];
        #pragma unroll
        for (int mt = 0; mt < 4; ++mt)
            aF[mt] = *(const bf16x8*)&sA[(mt * 16 + m) * LDB + k0];
        bf16x8 bF[2];
        #pragma unroll
        for (int nt = 0; nt < 2; ++nt) {
            int n = (wave << 5) + (nt << 4) + m;
            bF[nt] = *(const bf16x8*)&W2T[n * 128 + k0];
        }
        #pragma unroll
        for (int mt = 0; mt < 4; ++mt)
            #pragma unroll
            for (int nt = 0; nt < 2; ++nt)
                acc[mt][nt] = __builtin_amdgcn_mfma_f32_16x16x32_bf16(
                    aF[mt], bF[nt], acc[mt][nt], 0, 0, 0);
    }

    #pragma unroll
    for (int mt = 0; mt < 4; ++mt) {
        #pragma unroll
        for (int nt = 0; nt < 2; ++nt) {
            int col = (wave << 5) + (nt << 4) + m;
            #pragma unroll
            for (int i = 0; i < 4; ++i) {
                int rr = (mt << 4) + (q << 2) + i;
                if (r0 + rr < N) {
                    float v = acc[mt][nt][i];
                    node_out[(size_t)(r0 + rr) * H + col] = v > 0.f ? v : 0.f;
                }
            }
        }
    }
}

static inline size_t algn(size_t x) { return (x + 255) & ~(size_t)255; }

extern "C" void kernel_launch(void* const* d_in, const int* in_sizes, int n_in,
                              void* d_out, int out_size, void* d_ws, size_t ws_size,
                              hipStream_t stream) {
    const float* node_rep = (const float*)d_in[0];
    const float* edge_rep = (const float*)d_in[1];
    const int*   eidx     = (const int*)d_in[2];
    const float* W1       = (const float*)d_in[3];
    const float* W2       = (const float*)d_in[4];
    const float* WL       = (const float*)d_in[5];
    const float* eps1     = (const float*)d_in[6];
    const float* eps2     = (const float*)d_in[7];

    const int N = in_sizes[0] / H;     // 50000
    const int E = in_sizes[1] / H;     // 800000

    float* node_out = (float*)d_out;
    float* edge_out = (float*)d_out + (size_t)N * H;
    float* lvl = node_out;             // lvl aliases node_out (node_kernel is in-place safe)

    char* ws = (char*)d_ws;
    short* W1T = (short*)ws;                       // 64 KB
    short* W2T = (short*)(ws + 65536);             // 32 KB
    short* WLT = (short*)(ws + 65536 + 32768);     // 32 KB
    size_t off = 131072;

    int* deg       = (int*)(ws + off); off += algn((size_t)N * 4);
    int* row_start = (int*)(ws + off); off += algn((size_t)(N + 1) * 4);
    int* cursor    = (int*)(ws + off); off += algn((size_t)N * 4);
    int* csr       = (int*)(ws + off); off += algn((size_t)2 * E * 4);
    short* hbuf    = (short*)(ws + off); off += algn((size_t)E * H * sizeof(short));
    short* nodeB   = (short*)(ws + off); off += algn((size_t)N * H * sizeof(short));
    const size_t need_full = off;

    prep_weights<<<128, 256, 0, stream>>>(W1, W2, WL, W1T, W2T, WLT);

    const int twoE = 2 * E;
    const int egrid = (E + MB - 1) / MB;
    const int ngrid = (N + MB - 1) / MB;

    if (ws_size >= need_full) {
        // build CSR incidence lists (int atomics only: 2E ops)
        hipMemsetAsync(deg, 0, (size_t)N * 4, stream);
        count_deg<<<(twoE + 255) / 256, 256, 0, stream>>>(eidx, deg, twoE);
        scan_deg<<<1, 1024, 0, stream>>>(deg, row_start, cursor, N);
        fill_csr<<<(twoE + 255) / 256, 256, 0, stream>>>(eidx, cursor, csr, E);

        int total8 = (N * H) / 8;
        prep_nodes<<<(total8 + 255) / 256, 256, 0, stream>>>(node_rep, nodeB, total8);

        int nTiles = (E + MB - 1) / MB;
        int pgrid = (nTiles + TPB - 1) / TPB;
        edge_pipe<<<pgrid, 256, 0, stream>>>(
            nodeB, edge_rep, eidx, W1T, WLT, eps2, hbuf, edge_out, E, nTiles);

        node_aggr4<<<(N + 3) / 4, 256, 0, stream>>>(
            (const uint4*)hbuf, csr, row_start, lvl, N);
        node_kernel<<<ngrid, 256, 0, stream>>>(
            node_rep, lvl, W2T, eps1, node_out, N);
    } else {
        // LEGACY: atomic scatter
        hipMemsetAsync(lvl, 0, (size_t)N * H * sizeof(float), stream);
        edge_kernel<<<egrid, 256, 0, stream>>>(
            node_rep, edge_rep, eidx, W1T, WLT, eps2, lvl, edge_out, E);
        node_kernel<<<ngrid, 256, 0, stream>>>(
            node_rep, lvl, W2T, eps1, node_out, N);
    }
}

// Round 6
// 1267.949 us; speedup vs baseline: 1.3186x; 1.0502x over previous
//
#include <hip/hip_runtime.h>

#define H 128
#define MB 64          // edges (or nodes) per tile
#define TPB 4          // tiles per block in edge_pipe
#define LDA 264        // LDS row stride (elems) for the [64 x 256] concat tile (+8 pad)
#define LDB 136        // LDS row stride for [64 x 128] tiles (+8 pad)

typedef __attribute__((ext_vector_type(8))) short bf16x8;
typedef __attribute__((ext_vector_type(4))) short s16x4;
typedef __attribute__((ext_vector_type(4))) float f32x4;

__device__ __forceinline__ short f2bf(float f) {
    union { float f; unsigned u; } v; v.f = f;
    unsigned r = v.u + 0x7FFF + ((v.u >> 16) & 1);   // RTNE
    return (short)(r >> 16);
}
__device__ __forceinline__ float bf2f(short s) {
    union { unsigned u; float f; } v;
    v.u = ((unsigned)(unsigned short)s) << 16;
    return v.f;
}
__device__ __forceinline__ float bflo(unsigned u) {
    union { unsigned u; float f; } v; v.u = u << 16; return v.f;
}
__device__ __forceinline__ float bfhi(unsigned u) {
    union { unsigned u; float f; } v; v.u = u & 0xffff0000u; return v.f;
}

// ---------------- weight prep: fp32 [K,N] -> bf16 transposed [N,K] ----------------
__global__ __launch_bounds__(256) void prep_weights(
    const float* __restrict__ W1, const float* __restrict__ W2,
    const float* __restrict__ WL,
    short* __restrict__ W1T, short* __restrict__ W2T, short* __restrict__ WLT)
{
    int tid = blockIdx.x * 256 + threadIdx.x;      // 0..32767
    {   // W1: [256,128] -> W1T [128][256]
        int n = tid >> 8, k = tid & 255;
        W1T[n * 256 + k] = f2bf(W1[k * 128 + n]);
    }
    if (tid < 16384) {  // W2, W_lift: [128,128] -> [128][128]
        int n = tid >> 7, k = tid & 127;
        W2T[n * 128 + k] = f2bf(W2[k * 128 + n]);
        WLT[n * 128 + k] = f2bf(WL[k * 128 + n]);
    }
}

// node_rep fp32 -> bf16 copy (halves the gather bytes in the edge kernel)
__global__ __launch_bounds__(256) void prep_nodes(
    const float* __restrict__ nr, short* __restrict__ nodeB, int total8)
{
    int t = blockIdx.x * 256 + threadIdx.x;
    if (t >= total8) return;
    const float4* p = (const float4*)nr + (size_t)t * 2;
    float4 a = p[0], b = p[1];
    bf16x8 v = { f2bf(a.x), f2bf(a.y), f2bf(a.z), f2bf(a.w),
                 f2bf(b.x), f2bf(b.y), f2bf(b.z), f2bf(b.w) };
    *(bf16x8*)(nodeB + (size_t)t * 8) = v;
}

// ---------------- CSR build ----------------
__global__ __launch_bounds__(256) void count_deg(
    const int* __restrict__ eidx, int* __restrict__ deg, int twoE)
{
    int t = blockIdx.x * 256 + threadIdx.x;
    if (t < twoE) atomicAdd(&deg[eidx[t]], 1);
}

// single-block exclusive scan of deg[N] -> row_start[N+1] and cursor[N]
__global__ __launch_bounds__(1024) void scan_deg(
    const int* __restrict__ deg, int* __restrict__ row_start,
    int* __restrict__ cursor, int N)
{
    __shared__ int part[1024];
    const int t = threadIdx.x;
    const int chunk = (N + 1023) >> 10;
    const int b = t * chunk;
    const int e = (b + chunk < N) ? (b + chunk) : N;
    int s = 0;
    for (int j = b; j < e; ++j) s += deg[j];
    part[t] = s;
    __syncthreads();
    for (int off = 1; off < 1024; off <<= 1) {
        int v = part[t];
        int u = (t >= off) ? part[t - off] : 0;
        __syncthreads();
        part[t] = v + u;
        __syncthreads();
    }
    int run = (t == 0) ? 0 : part[t - 1];
    for (int j = b; j < e; ++j) {
        int d = deg[j];
        row_start[j] = run;
        cursor[j]    = run;
        run += d;
    }
    if (t == 1023) row_start[N] = part[1023];
}

__global__ __launch_bounds__(256) void fill_csr(
    const int* __restrict__ eidx, int* __restrict__ cursor,
    int* __restrict__ csr, int E)
{
    int t = blockIdx.x * 256 + threadIdx.x;
    if (t < 2 * E) {
        int node = eidx[t];
        int e = (t < E) ? t : (t - E);
        int pos = atomicAdd(&cursor[node], 1);
        csr[pos] = e;
    }
}

// ---------------- PATH A: pipelined fused edge kernel (v3: 8-wave blocks) ----
// 512 threads, each wave owns 16 output cols -> all register arrays halve vs v2
// (target VGPR <= 128 so the >128 allocation step isn't crossed; m69). Next
// tile's random nodeB gathers prefetch into regs under GEMM1. lift@WL folded
// into acc2 during GEMM1; h (bf16) written into the dead edge_rep half of sA;
// coalesced hbuf dump; GEMM2 h@WL; edge_out = relu(acc2 + e2*acc3).
__global__ __launch_bounds__(512) void edge_pipe(
    const short* __restrict__ nodeB, const float* __restrict__ edge_rep,
    const int* __restrict__ eidx,
    const short* __restrict__ W1T, const short* __restrict__ WLT,
    const float* __restrict__ eps2p,
    short* __restrict__ hbuf, float* __restrict__ edge_out,
    int E, int nTiles)
{
    __shared__ short sA[MB * LDA];   // cols [0,128)=lift, [128,256)=edge_rep then h

    const int tid  = threadIdx.x;
    const int row  = tid >> 3;          // 0..63 (8 threads per edge row)
    const int cs   = (tid & 7) << 4;    // 0,16,...,112
    const int wv   = tid >> 6;          // wave 0..7, owns cols [wv*16, wv*16+16)
    const int lane = tid & 63;
    const int m = lane & 15;            // A row / B col / D col
    const int q = lane >> 4;            // k-quad / D row group
    const float e2 = 1.f + eps2p[0];

    int t = blockIdx.x * TPB;
    if (t >= nTiles) return;
    const int tEnd = (t + TPB < nTiles) ? (t + TPB) : nTiles;

    // ---- prologue: gather tile t's node rows into registers (16B x2 each) ----
    bf16x8 pS[2], pD[2];
    bool pv;
    {
        int e = t * MB + row;
        pv = (e < E);
        if (pv) {
            int sIdx = eidx[e], dIdx = eidx[E + e];
            const bf16x8* sp = (const bf16x8*)(nodeB + (size_t)sIdx * H + cs);
            const bf16x8* dp = (const bf16x8*)(nodeB + (size_t)dIdx * H + cs);
            pS[0] = sp[0]; pS[1] = sp[1];
            pD[0] = dp[0]; pD[1] = dp[1];
        }
    }

    for (; t < tEnd; ++t) {
        const int e0 = t * MB;

        // ---- stage: lift from prefetched regs; edge_rep streamed ----
        {
            short* rowA = sA + row * LDA;
            if (pv) {
                const float4* ep = (const float4*)(edge_rep + (size_t)(e0 + row) * H + cs);
                float4 ev[4];
                #pragma unroll
                for (int j = 0; j < 4; ++j) ev[j] = ep[j];
                #pragma unroll
                for (int j = 0; j < 2; ++j) {
                    bf16x8 lift;
                    #pragma unroll
                    for (int k = 0; k < 8; ++k)
                        lift[k] = f2bf(bf2f(pS[j][k]) + bf2f(pD[j][k]));
                    *(bf16x8*)&rowA[cs + 8 * j] = lift;
                }
                #pragma unroll
                for (int j = 0; j < 4; ++j) {
                    float4 c = ev[j];
                    s16x4 er = { f2bf(c.x), f2bf(c.y), f2bf(c.z), f2bf(c.w) };
                    *(s16x4*)&rowA[H + cs + 4 * j] = er;
                }
            } else {
                s16x4 z = {0, 0, 0, 0};
                #pragma unroll
                for (int j = 0; j < 4; ++j) {
                    int cc = cs + 4 * j;
                    *(s16x4*)&rowA[cc]     = z;
                    *(s16x4*)&rowA[H + cc] = z;
                }
            }
        }
        __syncthreads();

        // ---- issue next tile's gathers (latency hidden under GEMM1) ----
        if (t + 1 < tEnd) {
            int e = (t + 1) * MB + row;
            pv = (e < E);
            if (pv) {
                int sIdx = eidx[e], dIdx = eidx[E + e];
                const bf16x8* sp = (const bf16x8*)(nodeB + (size_t)sIdx * H + cs);
                const bf16x8* dp = (const bf16x8*)(nodeB + (size_t)dIdx * H + cs);
                pS[0] = sp[0]; pS[1] = sp[1];
                pD[0] = dp[0]; pD[1] = dp[1];
            }
        }

        // ---- GEMM1: acc = concat @ W1T;  acc2 = lift @ WLT (ks<4 fold) ----
        f32x4 zero = {0.f, 0.f, 0.f, 0.f};
        f32x4 acc[4], acc2[4];
        #pragma unroll
        for (int mt = 0; mt < 4; ++mt) { acc[mt] = zero; acc2[mt] = zero; }

        #pragma unroll
        for (int ks = 0; ks < 8; ++ks) {
            int k0 = ks * 32 + q * 8;
            bf16x8 aF[4];
            #pragma unroll
            for (int mt = 0; mt < 4; ++mt)
                aF[mt] = *(const bf16x8*)&sA[(mt * 16 + m) * LDA + k0];
            bf16x8 bF = *(const bf16x8*)&W1T[(wv * 16 + m) * 256 + k0];
            #pragma unroll
            for (int mt = 0; mt < 4; ++mt)
                acc[mt] = __builtin_amdgcn_mfma_f32_16x16x32_bf16(
                    aF[mt], bF, acc[mt], 0, 0, 0);
            if (ks < 4) {
                bf16x8 bL = *(const bf16x8*)&WLT[(wv * 16 + m) * 128 + k0];
                #pragma unroll
                for (int mt = 0; mt < 4; ++mt)
                    acc2[mt] = __builtin_amdgcn_mfma_f32_16x16x32_bf16(
                        aF[mt], bL, acc2[mt], 0, 0, 0);
            }
        }
        __syncthreads();   // all waves done reading sA

        // ---- epilogue: h = relu(acc) -> bf16 into the dead edge_rep half ----
        {
            int col = wv * 16 + m;
            #pragma unroll
            for (int mt = 0; mt < 4; ++mt) {
                #pragma unroll
                for (int i = 0; i < 4; ++i) {
                    int rr = (mt << 4) + (q << 2) + i;
                    float h = acc[mt][i];
                    h = h > 0.f ? h : 0.f;
                    sA[rr * LDA + H + col] = f2bf(h);
                }
            }
        }
        __syncthreads();

        // ---- coalesced hbuf dump (32B/thread from LDS) ----
        if (e0 + row < E) {
            bf16x8 h0 = *(const bf16x8*)&sA[row * LDA + H + cs];
            bf16x8 h1 = *(const bf16x8*)&sA[row * LDA + H + cs + 8];
            *(bf16x8*)&hbuf[(size_t)(e0 + row) * H + cs]     = h0;
            *(bf16x8*)&hbuf[(size_t)(e0 + row) * H + cs + 8] = h1;
        }

        // ---- GEMM2: acc3 = h @ WLT; edge_out = relu(acc2 + e2*acc3) ----
        f32x4 acc3[4];
        #pragma unroll
        for (int mt = 0; mt < 4; ++mt) acc3[mt] = zero;

        #pragma unroll
        for (int ks = 0; ks < 4; ++ks) {
            int k0 = ks * 32 + q * 8;
            bf16x8 aF[4];
            #pragma unroll
            for (int mt = 0; mt < 4; ++mt)
                aF[mt] = *(const bf16x8*)&sA[(mt * 16 + m) * LDA + H + k0];
            bf16x8 bF = *(const bf16x8*)&WLT[(wv * 16 + m) * 128 + k0];
            #pragma unroll
            for (int mt = 0; mt < 4; ++mt)
                acc3[mt] = __builtin_amdgcn_mfma_f32_16x16x32_bf16(
                    aF[mt], bF, acc3[mt], 0, 0, 0);
        }

        {
            int col = wv * 16 + m;
            #pragma unroll
            for (int mt = 0; mt < 4; ++mt) {
                #pragma unroll
                for (int i = 0; i < 4; ++i) {
                    int rr = (mt << 4) + (q << 2) + i;
                    if (e0 + rr < E) {
                        float v = acc2[mt][i] + e2 * acc3[mt][i];
                        edge_out[(size_t)(e0 + rr) * H + col] = v > 0.f ? v : 0.f;
                    }
                }
            }
        }
        __syncthreads();   // GEMM2 + dump reads done before next stage overwrites sA
    }
}

// ---------------- node aggregation: quarter-wave per edge ----------------
__global__ __launch_bounds__(256) void node_aggr4(
    const uint4* __restrict__ hb, const int* __restrict__ csr,
    const int* __restrict__ row_start, float* __restrict__ lvl, int N)
{
    const int wid = threadIdx.x >> 6, lane = threadIdx.x & 63;
    const int n = blockIdx.x * 4 + wid;
    if (n >= N) return;
    const int qt = lane >> 4, li = lane & 15;    // lane covers cols li*8..li*8+7
    const int beg = row_start[n], end = row_start[n + 1];
    float a0 = 0.f, a1 = 0.f, a2 = 0.f, a3 = 0.f;
    float a4 = 0.f, a5 = 0.f, a6 = 0.f, a7 = 0.f;

    int i = beg;
    for (; i + 8 <= end; i += 8) {
        int eA = csr[i + qt], eB = csr[i + 4 + qt];
        uint4 vA = hb[(size_t)eA * 16 + li];
        uint4 vB = hb[(size_t)eB * 16 + li];
        a0 += bflo(vA.x) + bflo(vB.x);  a1 += bfhi(vA.x) + bfhi(vB.x);
        a2 += bflo(vA.y) + bflo(vB.y);  a3 += bfhi(vA.y) + bfhi(vB.y);
        a4 += bflo(vA.z) + bflo(vB.z);  a5 += bfhi(vA.z) + bfhi(vB.z);
        a6 += bflo(vA.w) + bflo(vB.w);  a7 += bfhi(vA.w) + bfhi(vB.w);
    }
    if (i + 4 <= end) {
        int eA = csr[i + qt];
        uint4 vA = hb[(size_t)eA * 16 + li];
        a0 += bflo(vA.x);  a1 += bfhi(vA.x);
        a2 += bflo(vA.y);  a3 += bfhi(vA.y);
        a4 += bflo(vA.z);  a5 += bfhi(vA.z);
        a6 += bflo(vA.w);  a7 += bfhi(vA.w);
        i += 4;
    }
    int rem = end - i;     // 0..3
    if (qt < rem) {
        int eA = csr[i + qt];
        uint4 vA = hb[(size_t)eA * 16 + li];
        a0 += bflo(vA.x);  a1 += bfhi(vA.x);
        a2 += bflo(vA.y);  a3 += bfhi(vA.y);
        a4 += bflo(vA.z);  a5 += bfhi(vA.z);
        a6 += bflo(vA.w);  a7 += bfhi(vA.w);
    }
    // reduce across the 4 quarters (lanes with same li)
    a0 += __shfl_xor(a0, 16); a1 += __shfl_xor(a1, 16);
    a2 += __shfl_xor(a2, 16); a3 += __shfl_xor(a3, 16);
    a4 += __shfl_xor(a4, 16); a5 += __shfl_xor(a5, 16);
    a6 += __shfl_xor(a6, 16); a7 += __shfl_xor(a7, 16);
    a0 += __shfl_xor(a0, 32); a1 += __shfl_xor(a1, 32);
    a2 += __shfl_xor(a2, 32); a3 += __shfl_xor(a3, 32);
    a4 += __shfl_xor(a4, 32); a5 += __shfl_xor(a5, 32);
    a6 += __shfl_xor(a6, 32); a7 += __shfl_xor(a7, 32);
    if (qt == 0) {
        float* dst = lvl + (size_t)n * H + li * 8;
        float4 o0; o0.x = a0; o0.y = a1; o0.z = a2; o0.w = a3;
        float4 o1; o1.x = a4; o1.y = a5; o1.z = a6; o1.w = a7;
        *(float4*)dst = o0;
        *(float4*)(dst + 4) = o1;
    }
}

// ---------------- LEGACY edge kernel (atomic scatter) -- tiny-ws fallback ----
__global__ __launch_bounds__(256) void edge_kernel(
    const float* __restrict__ node_rep, const float* __restrict__ edge_rep,
    const int* __restrict__ eidx,
    const short* __restrict__ W1T, const short* __restrict__ WLT,
    const float* __restrict__ eps2p,
    float* __restrict__ lvl, float* __restrict__ edge_out, int E)
{
    __shared__ short sA[MB * LDA];
    __shared__ short sB[MB * LDB];
    __shared__ int sSrc[MB], sDst[MB];

    const int tid = threadIdx.x;
    const int e0  = blockIdx.x * MB;
    const float e2 = 1.f + eps2p[0];
    {
        int row  = tid >> 2;
        int cseg = (tid & 3) << 5;
        int e = e0 + row;
        int sIdx = 0, dIdx = 0;
        bool ev = (e < E);
        if (ev) { sIdx = eidx[e]; dIdx = eidx[E + e]; }
        if ((tid & 3) == 0) { sSrc[row] = sIdx; sDst[row] = dIdx; }
        short* rowA = sA + row * LDA;
        if (ev) {
            const float4* sp = (const float4*)(node_rep + (size_t)sIdx * H + cseg);
            const float4* dp = (const float4*)(node_rep + (size_t)dIdx * H + cseg);
            const float4* ep = (const float4*)(edge_rep + (size_t)e * H + cseg);
            #pragma unroll
            for (int j = 0; j < 8; ++j) {
                float4 a = sp[j], b = dp[j], c = ep[j];
                int cc = cseg + 4 * j;
                s16x4 lift = { f2bf(a.x + b.x), f2bf(a.y + b.y),
                               f2bf(a.z + b.z), f2bf(a.w + b.w) };
                s16x4 er   = { f2bf(c.x), f2bf(c.y), f2bf(c.z), f2bf(c.w) };
                *(s16x4*)&rowA[cc]      = lift;
                *(s16x4*)&rowA[H + cc]  = er;
            }
        } else {
            s16x4 z = {0, 0, 0, 0};
            #pragma unroll
            for (int j = 0; j < 8; ++j) {
                int cc = cseg + 4 * j;
                *(s16x4*)&rowA[cc]     = z;
                *(s16x4*)&rowA[H + cc] = z;
            }
        }
    }
    __syncthreads();

    const int wave = tid >> 6;
    const int lane = tid & 63;
    const int m = lane & 15;
    const int q = lane >> 4;

    f32x4 zero = {0.f, 0.f, 0.f, 0.f};
    f32x4 acc[4][2];
    #pragma unroll
    for (int mt = 0; mt < 4; ++mt)
        #pragma unroll
        for (int nt = 0; nt < 2; ++nt) acc[mt][nt] = zero;

    #pragma unroll
    for (int ks = 0; ks < 8; ++ks) {
        int k0 = ks * 32 + q * 8;
        bf16x8 aF[4];
        #pragma unroll
        for (int mt = 0; mt < 4; ++mt)
            aF[mt] = *(const bf16x8*)&sA[(mt * 16 + m) * LDA + k0];
        bf16x8 bF[2];
        #pragma unroll
        for (int nt = 0; nt < 2; ++nt) {
            int n = (wave << 5) + (nt << 4) + m;
            bF[nt] = *(const bf16x8*)&W1T[n * 256 + k0];
        }
        #pragma unroll
        for (int mt = 0; mt < 4; ++mt)
            #pragma unroll
            for (int nt = 0; nt < 2; ++nt)
                acc[mt][nt] = __builtin_amdgcn_mfma_f32_16x16x32_bf16(
                    aF[mt], bF[nt], acc[mt][nt], 0, 0, 0);
    }

    #pragma unroll
    for (int mt = 0; mt < 4; ++mt) {
        #pragma unroll
        for (int nt = 0; nt < 2; ++nt) {
            int col = (wave << 5) + (nt << 4) + m;
            #pragma unroll
            for (int i = 0; i < 4; ++i) {
                int rr = (mt << 4) + (q << 2) + i;
                if (e0 + rr < E) {
                    float h = acc[mt][nt][i];
                    h = h > 0.f ? h : 0.f;
                    int sn = sSrc[rr], dn = sDst[rr];
                    atomicAdd(lvl + (size_t)sn * H + col, h);
                    atomicAdd(lvl + (size_t)dn * H + col, h);
                    float b2 = e2 * h + bf2f(sA[rr * LDA + col]);
                    sB[rr * LDB + col] = f2bf(b2);
                }
            }
        }
    }
    __syncthreads();

    f32x4 acc2[4][2];
    #pragma unroll
    for (int mt = 0; mt < 4; ++mt)
        #pragma unroll
        for (int nt = 0; nt < 2; ++nt) acc2[mt][nt] = zero;

    #pragma unroll
    for (int ks = 0; ks < 4; ++ks) {
        int k0 = ks * 32 + q * 8;
        bf16x8 aF[4];
        #pragma unroll
        for (int mt = 0; mt < 4; ++mt)
            aF[mt] = *(const bf16x8*)&sB[(mt * 16 + m) * LDB + k0];
        bf16x8 bF[2];
        #pragma unroll
        for (int nt = 0; nt < 2; ++nt) {
            int n = (wave << 5) + (nt << 4) + m;
            bF[nt] = *(const bf16x8*)&WLT[n * 128 + k0];
        }
        #pragma unroll
        for (int mt = 0; mt < 4; ++mt)
            #pragma unroll
            for (int nt = 0; nt < 2; ++nt)
                acc2[mt][nt] = __builtin_amdgcn_mfma_f32_16x16x32_bf16(
                    aF[mt], bF[nt], acc2[mt][nt], 0, 0, 0);
    }

    #pragma unroll
    for (int mt = 0; mt < 4; ++mt) {
        #pragma unroll
        for (int nt = 0; nt < 2; ++nt) {
            int col = (wave << 5) + (nt << 4) + m;
            #pragma unroll
            for (int i = 0; i < 4; ++i) {
                int rr = (mt << 4) + (q << 2) + i;
                if (e0 + rr < E) {
                    float v = acc2[mt][nt][i];
                    edge_out[(size_t)(e0 + rr) * H + col] = v > 0.f ? v : 0.f;
                }
            }
        }
    }
}

// ---------------- node kernel ----------------
// node_out = relu(((1+eps1)*node_rep + lvl) @ W2); lvl may alias node_out.
__global__ __launch_bounds__(256) void node_kernel(
    const float* __restrict__ node_rep, const float* __restrict__ lvl,
    const short* __restrict__ W2T, const float* __restrict__ eps1p,
    float* __restrict__ node_out, int N)
{
    __shared__ short sA[MB * LDB];

    const int tid = threadIdx.x;
    const int r0  = blockIdx.x * MB;
    const float e1 = 1.f + eps1p[0];

    {
        int row  = tid >> 2;
        int cseg = (tid & 3) << 5;
        int r = r0 + row;
        short* rowA = sA + row * LDB;
        if (r < N) {
            const float4* np = (const float4*)(node_rep + (size_t)r * H + cseg);
            const float4* lp = (const float4*)(lvl + (size_t)r * H + cseg);
            #pragma unroll
            for (int j = 0; j < 8; ++j) {
                float4 a = np[j], b = lp[j];
                int cc = cseg + 4 * j;
                s16x4 v = { f2bf(e1 * a.x + b.x), f2bf(e1 * a.y + b.y),
                            f2bf(e1 * a.z + b.z), f2bf(e1 * a.w + b.w) };
                *(s16x4*)&rowA[cc] = v;
            }
        } else {
            s16x4 z = {0, 0, 0, 0};
            #pragma unroll
            for (int j = 0; j < 8; ++j) *(s16x4*)&rowA[cseg + 4 * j] = z;
        }
    }
    __syncthreads();

    const int wave = tid >> 6;
    const int lane = tid & 63;
    const int m = lane & 15;
    const int q = lane >> 4;

    f32x4 zero = {0.f, 0.f, 0.f, 0.f};
    f32x4 acc[4][2];
    #pragma unroll
    for (int mt = 0; mt < 4; ++mt)
        #pragma unroll
        for (int nt = 0; nt < 2; ++nt) acc[mt][nt] = zero;

    #pragma unroll
    for (int ks = 0; ks < 4; ++ks) {
        int k0 = ks * 32 + q * 8;
        bf16x8 aF[4];
        #pragma unroll
        for (int mt = 0; mt < 4; ++mt)
            aF[mt] = *(const bf16x8*)&sA[(mt * 16 + m) * LDB + k0];
        bf16x8 bF[2];
        #pragma unroll
        for (int nt = 0; nt < 2; ++nt) {
            int n = (wave << 5) + (nt << 4) + m;
            bF[nt] = *(const bf16x8*)&W2T[n * 128 + k0];
        }
        #pragma unroll
        for (int mt = 0; mt < 4; ++mt)
            #pragma unroll
            for (int nt = 0; nt < 2; ++nt)
                acc[mt][nt] = __builtin_amdgcn_mfma_f32_16x16x32_bf16(
                    aF[mt], bF[nt], acc[mt][nt], 0, 0, 0);
    }

    #pragma unroll
    for (int mt = 0; mt < 4; ++mt) {
        #pragma unroll
        for (int nt = 0; nt < 2; ++nt) {
            int col = (wave << 5) + (nt << 4) + m;
            #pragma unroll
            for (int i = 0; i < 4; ++i) {
                int rr = (mt << 4) + (q << 2) + i;
                if (r0 + rr < N) {
                    float v = acc[mt][nt][i];
                    node_out[(size_t)(r0 + rr) * H + col] = v > 0.f ? v : 0.f;
                }
            }
        }
    }
}

static inline size_t algn(size_t x) { return (x + 255) & ~(size_t)255; }

extern "C" void kernel_launch(void* const* d_in, const int* in_sizes, int n_in,
                              void* d_out, int out_size, void* d_ws, size_t ws_size,
                              hipStream_t stream) {
    const float* node_rep = (const float*)d_in[0];
    const float* edge_rep = (const float*)d_in[1];
    const int*   eidx     = (const int*)d_in[2];
    const float* W1       = (const float*)d_in[3];
    const float* W2       = (const float*)d_in[4];
    const float* WL       = (const float*)d_in[5];
    const float* eps1     = (const float*)d_in[6];
    const float* eps2     = (const float*)d_in[7];

    const int N = in_sizes[0] / H;     // 50000
    const int E = in_sizes[1] / H;     // 800000

    float* node_out = (float*)d_out;
    float* edge_out = (float*)d_out + (size_t)N * H;
    float* lvl = node_out;             // lvl aliases node_out (node_kernel is in-place safe)

    char* ws = (char*)d_ws;
    short* W1T = (short*)ws;                       // 64 KB
    short* W2T = (short*)(ws + 65536);             // 32 KB
    short* WLT = (short*)(ws + 65536 + 32768);     // 32 KB
    size_t off = 131072;

    int* deg       = (int*)(ws + off); off += algn((size_t)N * 4);
    int* row_start = (int*)(ws + off); off += algn((size_t)(N + 1) * 4);
    int* cursor    = (int*)(ws + off); off += algn((size_t)N * 4);
    int* csr       = (int*)(ws + off); off += algn((size_t)2 * E * 4);
    short* hbuf    = (short*)(ws + off); off += algn((size_t)E * H * sizeof(short));
    short* nodeB   = (short*)(ws + off); off += algn((size_t)N * H * sizeof(short));
    const size_t need_full = off;

    prep_weights<<<128, 256, 0, stream>>>(W1, W2, WL, W1T, W2T, WLT);

    const int twoE = 2 * E;
    const int egrid = (E + MB - 1) / MB;
    const int ngrid = (N + MB - 1) / MB;

    if (ws_size >= need_full) {
        // build CSR incidence lists (int atomics only: 2E ops)
        hipMemsetAsync(deg, 0, (size_t)N * 4, stream);
        count_deg<<<(twoE + 255) / 256, 256, 0, stream>>>(eidx, deg, twoE);
        scan_deg<<<1, 1024, 0, stream>>>(deg, row_start, cursor, N);
        fill_csr<<<(twoE + 255) / 256, 256, 0, stream>>>(eidx, cursor, csr, E);

        int total8 = (N * H) / 8;
        prep_nodes<<<(total8 + 255) / 256, 256, 0, stream>>>(node_rep, nodeB, total8);

        int nTiles = (E + MB - 1) / MB;
        int pgrid = (nTiles + TPB - 1) / TPB;
        edge_pipe<<<pgrid, 512, 0, stream>>>(
            nodeB, edge_rep, eidx, W1T, WLT, eps2, hbuf, edge_out, E, nTiles);

        node_aggr4<<<(N + 3) / 4, 256, 0, stream>>>(
            (const uint4*)hbuf, csr, row_start, lvl, N);
        node_kernel<<<ngrid, 256, 0, stream>>>(
            node_rep, lvl, W2T, eps1, node_out, N);
    } else {
        // LEGACY: atomic scatter
        hipMemsetAsync(lvl, 0, (size_t)N * H * sizeof(float), stream);
        edge_kernel<<<egrid, 256, 0, stream>>>(
            node_rep, edge_rep, eidx, W1T, WLT, eps2, lvl, edge_out, E);
        node_kernel<<<ngrid, 256, 0, stream>>>(
            node_rep, lvl, W2T, eps1, node_out, N);
    }
}